// Round 13
// baseline (269.519 us; speedup 1.0000x reference)
//
#include <hip/hip_runtime.h>
#include <math.h>

#define S_LEN 2048
#define DIM   1024
#define HEADS 16
#define DK    64
#define BATCH 4

typedef __bf16 bf16;
typedef bf16  bf16x8 __attribute__((ext_vector_type(8)));
typedef bf16  bf16x4 __attribute__((ext_vector_type(4)));
typedef float f32x4  __attribute__((ext_vector_type(4)));
typedef unsigned long long u64;

#define QSCALE (0.125f * 1.44269504088896f)   // 1/sqrt(dk) * log2(e)

__device__ __forceinline__ void gload16(const void* g, void* l) {
  __builtin_amdgcn_global_load_lds((const __attribute__((address_space(1))) void*)g,
                                   (__attribute__((address_space(3))) void*)l, 16, 0, 0);
}
__device__ __forceinline__ float exp2fast(float x) {
  float r; asm("v_exp_f32 %0, %1" : "=v"(r) : "v"(x)); return r;
}
__device__ __forceinline__ unsigned cvt_pk_bf16(float a, float b) {
  unsigned r; asm("v_cvt_pk_bf16_f32 %0, %1, %2" : "=v"(r) : "v"(a), "v"(b)); return r;
}

// ---------------------------------------------------------------------------
// f32 -> bf16 conversion, all 7 tensors in one launch.
// y<3: q/k/v (4096 blocks each). y==3: Wq/Wk/Wv/Wo (512 blocks each).
// ---------------------------------------------------------------------------
__global__ __launch_bounds__(256)
void conv_all(const float* __restrict__ q, const float* __restrict__ k,
              const float* __restrict__ v,
              const float* __restrict__ Wq, const float* __restrict__ Wk,
              const float* __restrict__ Wv, const float* __restrict__ Wo,
              bf16* __restrict__ qB, bf16* __restrict__ kB, bf16* __restrict__ vB,
              bf16* __restrict__ WqB, bf16* __restrict__ WkB,
              bf16* __restrict__ WvB, bf16* __restrict__ WoB)
{
  const int y = blockIdx.y;
  const float* in;
  bf16* out;
  size_t idx;
  if (y < 3) {
    in  = (y == 0) ? q  : (y == 1) ? k  : v;
    out = (y == 0) ? qB : (y == 1) ? kB : vB;
    idx = ((size_t)blockIdx.x * 256 + threadIdx.x) * 8;
  } else {
    if (blockIdx.x >= 2048) return;
    const int wsel = blockIdx.x >> 9, inner = blockIdx.x & 511;
    in  = (wsel == 0) ? Wq  : (wsel == 1) ? Wk  : (wsel == 2) ? Wv  : Wo;
    out = (wsel == 0) ? WqB : (wsel == 1) ? WkB : (wsel == 2) ? WvB : WoB;
    idx = ((size_t)inner * 256 + threadIdx.x) * 8;
  }
  float4 a = *reinterpret_cast<const float4*>(&in[idx]);
  float4 b = *reinterpret_cast<const float4*>(&in[idx + 4]);
  bf16x8 r;
  r[0] = (bf16)a.x; r[1] = (bf16)a.y; r[2] = (bf16)a.z; r[3] = (bf16)a.w;
  r[4] = (bf16)b.x; r[5] = (bf16)b.y; r[6] = (bf16)b.z; r[7] = (bf16)b.w;
  *reinterpret_cast<bf16x8*>(&out[idx]) = r;
}

// ---------------------------------------------------------------------------
// FUSED dispatch: mask bitpack (blocks 0..511, BW-bound) + the three QKV
// projection GEMMs (blocks 512..2047, compute-bound). The pack blocks'
// HBM traffic hides under the GEMM blocks' MFMA work, and the three GEMMs
// share one block supply (one tail instead of three + no launch gaps).
// GEMM: C = A @ W^T + bias, 128x128 tile, BK=64, XCD-chunked swizzle,
// global_load_lds + XOR swizzle, double-buffered (round-8 structure).
// which==0: out=Qb scaled by QSCALE | 1: out=Kb | 2: out=Vt k-permuted.
// ---------------------------------------------------------------------------
#define GSTAGE(K0, NB) do {                                                    \
    _Pragma("unroll")                                                          \
    for (int j = 0; j < 4; ++j) {                                              \
      const int chunk = j * 256 + tid;                                         \
      const int rr = chunk >> 3;                                               \
      const int cG = ((chunk & 7) << 4) ^ ((rr & 7) << 4);                     \
      gload16(Ab + ((size_t)(m0 + rr) * 1024 + (K0)) * 2 + cG,                 \
              (char*)&As[NB][0][0] + chunk * 16);                              \
      gload16(Wb + ((size_t)(n0 + rr) * 1024 + (K0)) * 2 + cG,                 \
              (char*)&Bs[NB][0][0] + chunk * 16);                              \
    }                                                                          \
  } while (0)

__global__ __launch_bounds__(256)
void fused_qkv_pack(const bf16* __restrict__ qB, const bf16* __restrict__ kB,
                    const bf16* __restrict__ vB,
                    const bf16* __restrict__ WqB, const bf16* __restrict__ WkB,
                    const bf16* __restrict__ WvB,
                    const float* __restrict__ bq, const float* __restrict__ bk,
                    const float* __restrict__ bv,
                    bf16* __restrict__ Qb, bf16* __restrict__ Kb,
                    bf16* __restrict__ Vt,
                    const int* __restrict__ mask, u64* __restrict__ bits)
{
  __shared__ __align__(16) bf16 As[2][128][64];
  __shared__ __align__(16) bf16 Bs[2][128][64];
  const int tid = threadIdx.x;

  if (blockIdx.x < 512) {
    // ---- mask bitpack: 512 u64 words (32768 ints) per block ----
    const int lane = tid & 63;
    const size_t w0 = (size_t)blockIdx.x * 512 + (tid >> 6);
    #pragma unroll 4
    for (int it = 0; it < 128; ++it) {
      const size_t w = w0 + it * 4;
      const int mv = mask[w * 64 + lane];
      const u64 bb = __ballot(mv != 0);
      if (lane == 0) bits[w] = bb;
    }
    return;
  }

  // ---- GEMM path ----
  const int gx = blockIdx.x - 512;
  const int which = gx >> 9;            // 0:Q 1:K 2:V (block-uniform)
  const int inner = gx & 511;
  const bf16* A    = (which == 0) ? qB  : (which == 1) ? kB  : vB;
  const bf16* W    = (which == 0) ? WqB : (which == 1) ? WkB : WvB;
  const float* bias = (which == 0) ? bq : (which == 1) ? bk  : bv;

  const int lane = tid & 63, wid = tid >> 6;
  const int l15  = lane & 15, lg = lane >> 4;
  const int L  = (inner & 7) * 64 + (inner >> 3);   // XCD-chunked
  const int m0 = (L >> 3) * 128, n0 = (L & 7) * 128;
  const int wm = wid >> 1, wn = wid & 1;
  const char* Ab = (const char*)A;
  const char* Wb = (const char*)W;

  f32x4 acc[4][4] = {};

  GSTAGE(0, 0);
  asm volatile("s_waitcnt vmcnt(0)" ::: "memory");
  __syncthreads();

  int cur = 0;
  const int NT = 1024 >> 6;   // 16
  for (int t = 0; t < NT; ++t) {
    if (t + 1 < NT) GSTAGE((t + 1) << 6, cur ^ 1);

    bf16x8 af[4][2], bfr[4][2];
    #pragma unroll
    for (int i = 0; i < 4; ++i) {
      const int ra = wm * 64 + i * 16 + l15;
      const int rb = wn * 64 + i * 16 + l15;
      #pragma unroll
      for (int s = 0; s < 2; ++s) {
        const int co = (s * 64 + lg * 16);
        af[i][s]  = *reinterpret_cast<const bf16x8*>(
            (const char*)&As[cur][0][0] + ra * 128 + (co ^ ((ra & 7) << 4)));
        bfr[i][s] = *reinterpret_cast<const bf16x8*>(
            (const char*)&Bs[cur][0][0] + rb * 128 + (co ^ ((rb & 7) << 4)));
      }
    }
    __builtin_amdgcn_s_setprio(1);
    #pragma unroll
    for (int s = 0; s < 2; ++s)
      #pragma unroll
      for (int mi = 0; mi < 4; ++mi)
        #pragma unroll
        for (int ni = 0; ni < 4; ++ni)
          acc[mi][ni] = __builtin_amdgcn_mfma_f32_16x16x32_bf16(af[mi][s], bfr[ni][s], acc[mi][ni], 0, 0, 0);
    __builtin_amdgcn_s_setprio(0);

    asm volatile("s_waitcnt vmcnt(0)" ::: "memory");
    __syncthreads();
    cur ^= 1;
  }

  // epilogue: C row = lg*4 + reg, col = l15 within each 16x16 fragment
  #pragma unroll
  for (int ni = 0; ni < 4; ++ni) {
    const int col = n0 + wn * 64 + ni * 16 + l15;
    const float bi = bias[col];
    #pragma unroll
    for (int mi = 0; mi < 4; ++mi) {
      const int row0 = m0 + wm * 64 + mi * 16 + lg * 4;
      if (which == 0) {
        #pragma unroll
        for (int r = 0; r < 4; ++r)
          Qb[(size_t)(row0 + r) * DIM + col] = (bf16)((acc[mi][ni][r] + bi) * QSCALE);
      } else if (which == 1) {
        #pragma unroll
        for (int r = 0; r < 4; ++r)
          Kb[(size_t)(row0 + r) * DIM + col] = (bf16)(acc[mi][ni][r] + bi);
      } else {
        bf16x4 vv;
        #pragma unroll
        for (int r = 0; r < 4; ++r) vv[r] = (bf16)(acc[mi][ni][r] + bi);
        const int seq = row0 & (S_LEN - 1);
        const int t6  = seq & 63;
        const int p0  = (seq & ~63) + ((t6 >> 5) << 5) + (((t6 >> 2) & 3) << 3)
                      + (((t6 >> 4) & 1) << 2);
        *reinterpret_cast<bf16x4*>(
            &Vt[((size_t)(row0 >> 11) * DIM + col) * S_LEN + p0]) = vv;
      }
    }
  }
}

// ---------------------------------------------------------------------------
// O-projection GEMM (f32 out), same structure, standalone.
// ---------------------------------------------------------------------------
__global__ __launch_bounds__(256)
void gemm_out(const bf16* __restrict__ A, const bf16* __restrict__ W,
              const float* __restrict__ bias, float* __restrict__ out)
{
  __shared__ __align__(16) bf16 As[2][128][64];
  __shared__ __align__(16) bf16 Bs[2][128][64];
  const int tid  = threadIdx.x;
  const int lane = tid & 63, wid = tid >> 6;
  const int l15  = lane & 15, lg = lane >> 4;
  const int L  = (blockIdx.x & 7) * 64 + (blockIdx.x >> 3);
  const int m0 = (L >> 3) * 128, n0 = (L & 7) * 128;
  const int wm = wid >> 1, wn = wid & 1;
  const char* Ab = (const char*)A;
  const char* Wb = (const char*)W;

  f32x4 acc[4][4] = {};

  GSTAGE(0, 0);
  asm volatile("s_waitcnt vmcnt(0)" ::: "memory");
  __syncthreads();

  int cur = 0;
  const int NT = 1024 >> 6;
  for (int t = 0; t < NT; ++t) {
    if (t + 1 < NT) GSTAGE((t + 1) << 6, cur ^ 1);

    bf16x8 af[4][2], bfr[4][2];
    #pragma unroll
    for (int i = 0; i < 4; ++i) {
      const int ra = wm * 64 + i * 16 + l15;
      const int rb = wn * 64 + i * 16 + l15;
      #pragma unroll
      for (int s = 0; s < 2; ++s) {
        const int co = (s * 64 + lg * 16);
        af[i][s]  = *reinterpret_cast<const bf16x8*>(
            (const char*)&As[cur][0][0] + ra * 128 + (co ^ ((ra & 7) << 4)));
        bfr[i][s] = *reinterpret_cast<const bf16x8*>(
            (const char*)&Bs[cur][0][0] + rb * 128 + (co ^ ((rb & 7) << 4)));
      }
    }
    __builtin_amdgcn_s_setprio(1);
    #pragma unroll
    for (int s = 0; s < 2; ++s)
      #pragma unroll
      for (int mi = 0; mi < 4; ++mi)
        #pragma unroll
        for (int ni = 0; ni < 4; ++ni)
          acc[mi][ni] = __builtin_amdgcn_mfma_f32_16x16x32_bf16(af[mi][s], bfr[ni][s], acc[mi][ni], 0, 0, 0);
    __builtin_amdgcn_s_setprio(0);

    asm volatile("s_waitcnt vmcnt(0)" ::: "memory");
    __syncthreads();
    cur ^= 1;
  }

  #pragma unroll
  for (int ni = 0; ni < 4; ++ni) {
    const int col = n0 + wn * 64 + ni * 16 + l15;
    const float bi = bias[col];
    #pragma unroll
    for (int mi = 0; mi < 4; ++mi) {
      const int row0 = m0 + wm * 64 + mi * 16 + lg * 4;
      #pragma unroll
      for (int r = 0; r < 4; ++r)
        out[(size_t)(row0 + r) * DIM + col] = acc[mi][ni][r] + bi;
    }
  }
}

// ---------------------------------------------------------------------------
// Flash attention (unchanged from round 12): static-max softmax, prescaled Q,
// P in registers via cvt_pk + k-permuted V, hoisted addresses, packed-AND
// mask, double-buffered K/V via global_load_lds + XOR swizzle.
// ---------------------------------------------------------------------------
__global__ __launch_bounds__(512, 4)
void attn_fwd(const bf16* __restrict__ Qb, const bf16* __restrict__ Kb,
              const bf16* __restrict__ Vt, const u64* __restrict__ mbits,
              bf16* __restrict__ ctx)
{
  __shared__ __align__(16) bf16 Kbuf[2][64][64];
  __shared__ __align__(16) bf16 Vbuf[2][64][64];

  const int tid  = threadIdx.x;
  const int lane = tid & 63;
  const int l15  = lane & 15, lg = lane >> 4;
  const int L  = (blockIdx.x & 7) * 64 + (blockIdx.x >> 3);
  const int qi = L & 7;
  const int hb = L >> 3;
  const int h  = hb & 15, b = hb >> 4;
  const int w  = tid >> 6;
  const int qbase = qi * 256 + w * 32;

  const int rr_s = tid >> 3;
  const int cG_s = ((tid & 7) << 4) ^ ((rr_s & 7) << 4);
  const char* gk = (const char*)Kb + ((size_t)(b * S_LEN + rr_s) * DIM + h * DK) * 2 + cG_s;
  const char* gv = (const char*)Vt + ((size_t)b * DIM + h * DK + rr_s) * (S_LEN * 2) + cG_s;
  char* lK = (char*)&Kbuf[0][0][0] + tid * 16;
  char* lV = (char*)&Vbuf[0][0][0] + tid * 16;

  const unsigned xo  = (l15 & 7) << 4;
  const unsigned ko0 = l15 * 128 + ((lg * 16) ^ xo);
  const unsigned ko1 = l15 * 128 + (((64 + lg * 16)) ^ xo);
  const char* KB = (const char*)&Kbuf[0][0][0];
  const char* VB = (const char*)&Vbuf[0][0][0];

  bf16x8 qf[2][2];
  #pragma unroll
  for (int qg = 0; qg < 2; ++qg) {
    const size_t qrow = (size_t)b * S_LEN + qbase + qg * 16 + l15;
    #pragma unroll
    for (int s = 0; s < 2; ++s)
      qf[qg][s] = *reinterpret_cast<const bf16x8*>(&Qb[qrow * DIM + h * DK + s * 32 + lg * 8]);
  }

  bf16x8 onesf;
  #pragma unroll
  for (int j = 0; j < 8; ++j) onesf[j] = (bf16)1.0f;

  union pqu { unsigned u[8]; bf16x8 frag[2]; };

  f32x4 o[2][4] = {};
  f32x4 o_l[2] = {};
  const u64* mp0 = mbits + ((size_t)b * S_LEN + qbase + l15) * (S_LEN / 64);
  const u64* mp1 = mp0 + (size_t)16 * (S_LEN / 64);

  gload16(gk, lK);  gload16(gv, lV);
  gk += 64 * DIM * 2;  gv += 64 * 2;
  u64 mbc[2] = { mp0[0], mp1[0] };
  mp0++; mp1++;

  const int NT = S_LEN / 64;   // 32
  for (int t = 0; t < NT; ++t) {
    asm volatile("s_waitcnt vmcnt(0)" ::: "memory");
    __syncthreads();

    u64 mbn[2] = {0, 0};
    if (t + 1 < NT) {
      mbn[0] = *mp0++;
      mbn[1] = *mp1++;
      const unsigned nb = ((t + 1) & 1) << 13;
      gload16(gk, lK + nb);
      gload16(gv, lV + nb);
      gk += 64 * DIM * 2;
      gv += 64 * 2;
    }

    const unsigned tb = (t & 1) << 13;

    f32x4 sc[2][4] = {};
    __builtin_amdgcn_s_setprio(1);
    #pragma unroll
    for (int s = 0; s < 2; ++s) {
      const char* kp = KB + tb + (s ? ko1 : ko0);
      #pragma unroll
      for (int nf = 0; nf < 4; ++nf) {
        bf16x8 kf = *reinterpret_cast<const bf16x8*>(kp + nf * 2048);
        sc[0][nf] = __builtin_amdgcn_mfma_f32_16x16x32_bf16(kf, qf[0][s], sc[0][nf], 0, 0, 0);
        sc[1][nf] = __builtin_amdgcn_mfma_f32_16x16x32_bf16(kf, qf[1][s], sc[1][nf], 0, 0, 0);
      }
    }
    __builtin_amdgcn_s_setprio(0);

    pqu W[2];
    #pragma unroll
    for (int qg = 0; qg < 2; ++qg) {
      #pragma unroll
      for (int nf = 0; nf < 4; ++nf) {
        const unsigned mm = (unsigned)(mbc[qg] >> (nf * 16 + lg * 4));
        float e0 = exp2fast(sc[qg][nf][0]);
        float e1 = exp2fast(sc[qg][nf][1]);
        float e2 = exp2fast(sc[qg][nf][2]);
        float e3 = exp2fast(sc[qg][nf][3]);
        const unsigned m01 = ((unsigned)(((int)(mm << 31)) >> 31) & 0x0000FFFFu)
                           | ((unsigned)(((int)(mm << 30)) >> 31) & 0xFFFF0000u);
        const unsigned m23 = ((unsigned)(((int)(mm << 29)) >> 31) & 0x0000FFFFu)
                           | ((unsigned)(((int)(mm << 28)) >> 31) & 0xFFFF0000u);
        W[qg].u[nf * 2 + 0] = cvt_pk_bf16(e0, e1) & m01;
        W[qg].u[nf * 2 + 1] = cvt_pk_bf16(e2, e3) & m23;
      }
    }

    __builtin_amdgcn_s_setprio(1);
    #pragma unroll
    for (int s = 0; s < 2; ++s) {
      const char* vp = VB + tb + (s ? ko1 : ko0);
      #pragma unroll
      for (int nf = 0; nf < 4; ++nf) {
        bf16x8 vf = *reinterpret_cast<const bf16x8*>(vp + nf * 2048);
        o[0][nf] = __builtin_amdgcn_mfma_f32_16x16x32_bf16(W[0].frag[s], vf, o[0][nf], 0, 0, 0);
        o[1][nf] = __builtin_amdgcn_mfma_f32_16x16x32_bf16(W[1].frag[s], vf, o[1][nf], 0, 0, 0);
      }
      o_l[0] = __builtin_amdgcn_mfma_f32_16x16x32_bf16(W[0].frag[s], onesf, o_l[0], 0, 0, 0);
      o_l[1] = __builtin_amdgcn_mfma_f32_16x16x32_bf16(W[1].frag[s], onesf, o_l[1], 0, 0, 0);
    }
    __builtin_amdgcn_s_setprio(0);

    mbc[0] = mbn[0]; mbc[1] = mbn[1];
  }

  #pragma unroll
  for (int qg = 0; qg < 2; ++qg) {
    float lf[4];
    #pragma unroll
    for (int r = 0; r < 4; ++r) lf[r] = 1.0f / o_l[qg][r];
    #pragma unroll
    for (int nf = 0; nf < 4; ++nf)
      #pragma unroll
      for (int r = 0; r < 4; ++r) {
        const int q = qbase + qg * 16 + lg * 4 + r;
        ctx[((size_t)b * S_LEN + q) * DIM + h * DK + nf * 16 + l15] = (bf16)(o[qg][nf][r] * lf[r]);
      }
  }
}

// ---------------------------------------------------------------------------
extern "C" void kernel_launch(void* const* d_in, const int* in_sizes, int n_in,
                              void* d_out, int out_size, void* d_ws, size_t ws_size,
                              hipStream_t stream)
{
  const float* q    = (const float*)d_in[0];
  const float* k    = (const float*)d_in[1];
  const float* v    = (const float*)d_in[2];
  const int*   mask = (const int*)  d_in[3];
  const float* Wq   = (const float*)d_in[4];
  const float* bq   = (const float*)d_in[5];
  const float* Wk   = (const float*)d_in[6];
  const float* bk   = (const float*)d_in[7];
  const float* Wv   = (const float*)d_in[8];
  const float* bv   = (const float*)d_in[9];
  const float* Wo   = (const float*)d_in[10];
  const float* bo   = (const float*)d_in[11];
  float* out = (float*)d_out;

  const size_t NE = (size_t)BATCH * S_LEN * DIM;  // 8.39M elements
  const size_t NW = (size_t)DIM * DIM;            // 1.05M elements
  bf16* qB  = (bf16*)d_ws;                        // bf16 copies of inputs
  bf16* kB  = qB + NE;
  bf16* vB  = kB + NE;
  bf16* Qb  = vB + NE;                            // projected Q,K,V
  bf16* Kb  = Qb + NE;
  bf16* Vt  = Kb + NE;
  bf16* WqB = Vt + NE;                            // bf16 weights
  bf16* WkB = WqB + NW;
  bf16* WvB = WkB + NW;
  bf16* WoB = WvB + NW;
  u64*  bits = (u64*)(WoB + NW);                  // 2 MB
  bf16* ctx = qB;                                 // reuse: qB dead after QKV GEMMs

  conv_all<<<dim3(4096, 4), 256, 0, stream>>>(q, k, v, Wq, Wk, Wv, Wo,
                                              qB, kB, vB, WqB, WkB, WvB, WoB);

  fused_qkv_pack<<<2048, 256, 0, stream>>>(qB, kB, vB, WqB, WkB, WvB,
                                           bq, bk, bv, Qb, Kb, Vt, mask, bits);

  attn_fwd<<<512, 512, 0, stream>>>(Qb, Kb, Vt, bits, ctx);

  gemm_out<<<512, 256, 0, stream>>>(ctx, WoB, bo, out);
}

// Round 14
// 238.158 us; speedup vs baseline: 1.1317x; 1.1317x over previous
//
#include <hip/hip_runtime.h>
#include <math.h>

#define S_LEN 2048
#define DIM   1024
#define HEADS 16
#define DK    64
#define BATCH 4

typedef __bf16 bf16;
typedef bf16  bf16x8 __attribute__((ext_vector_type(8)));
typedef bf16  bf16x4 __attribute__((ext_vector_type(4)));
typedef float f32x4  __attribute__((ext_vector_type(4)));
typedef unsigned long long u64;

#define QSCALE (0.125f * 1.44269504088896f)   // 1/sqrt(dk) * log2(e)

__device__ __forceinline__ void gload16(const void* g, void* l) {
  __builtin_amdgcn_global_load_lds((const __attribute__((address_space(1))) void*)g,
                                   (__attribute__((address_space(3))) void*)l, 16, 0, 0);
}
__device__ __forceinline__ float exp2fast(float x) {
  float r; asm("v_exp_f32 %0, %1" : "=v"(r) : "v"(x)); return r;
}
__device__ __forceinline__ unsigned cvt_pk_bf16(float a, float b) {
  unsigned r; asm("v_cvt_pk_bf16_f32 %0, %1, %2" : "=v"(r) : "v"(a), "v"(b)); return r;
}

// ---------------------------------------------------------------------------
// Mask bitpack: 67 MB int32 -> 2 MB u64 bitmask (L2-resident). Short blocks
// (1 ballot per wave) -- NOT fused with compute (round-13 lesson: long serial
// pack blocks straggle and starve the MFMA pipe).
// ---------------------------------------------------------------------------
__global__ __launch_bounds__(256)
void pack_mask(const int* __restrict__ mask, u64* __restrict__ bits)
{
  const int w    = blockIdx.x * 4 + (threadIdx.x >> 6);
  const int lane = threadIdx.x & 63;
  const int mv   = mask[(size_t)w * 64 + lane];
  const u64 b    = __ballot(mv != 0);
  if (lane == 0) bits[w] = b;
}

// ---------------------------------------------------------------------------
// f32 -> bf16 conversion, all 7 tensors in one launch.
// y<3: q/k/v (4096 blocks each). y==3: Wq/Wk/Wv/Wo (512 blocks each).
// ---------------------------------------------------------------------------
__global__ __launch_bounds__(256)
void conv_all(const float* __restrict__ q, const float* __restrict__ k,
              const float* __restrict__ v,
              const float* __restrict__ Wq, const float* __restrict__ Wk,
              const float* __restrict__ Wv, const float* __restrict__ Wo,
              bf16* __restrict__ qB, bf16* __restrict__ kB, bf16* __restrict__ vB,
              bf16* __restrict__ WqB, bf16* __restrict__ WkB,
              bf16* __restrict__ WvB, bf16* __restrict__ WoB)
{
  const int y = blockIdx.y;
  const float* in;
  bf16* out;
  size_t idx;
  if (y < 3) {
    in  = (y == 0) ? q  : (y == 1) ? k  : v;
    out = (y == 0) ? qB : (y == 1) ? kB : vB;
    idx = ((size_t)blockIdx.x * 256 + threadIdx.x) * 8;
  } else {
    if (blockIdx.x >= 2048) return;
    const int wsel = blockIdx.x >> 9, inner = blockIdx.x & 511;
    in  = (wsel == 0) ? Wq  : (wsel == 1) ? Wk  : (wsel == 2) ? Wv  : Wo;
    out = (wsel == 0) ? WqB : (wsel == 1) ? WkB : (wsel == 2) ? WvB : WoB;
    idx = ((size_t)inner * 256 + threadIdx.x) * 8;
  }
  float4 a = *reinterpret_cast<const float4*>(&in[idx]);
  float4 b = *reinterpret_cast<const float4*>(&in[idx + 4]);
  bf16x8 r;
  r[0] = (bf16)a.x; r[1] = (bf16)a.y; r[2] = (bf16)a.z; r[3] = (bf16)a.w;
  r[4] = (bf16)b.x; r[5] = (bf16)b.y; r[6] = (bf16)b.z; r[7] = (bf16)b.w;
  *reinterpret_cast<bf16x8*>(&out[idx]) = r;
}

// ---------------------------------------------------------------------------
// bf16 NT GEMM: C[M][N] = A[M][K] @ W[N][K]^T + bias[N]
// MODE 0: bf16 out | 1: bf16 out transposed + k-PERMUTED Vt[b][n][perm(seq)]
// MODE 2: f32 out | MODE 3: bf16 out scaled by QSCALE (Q projection)
// 1D grid 512, XCD-chunked swizzle; 128x128 tile, BK=64, global_load_lds +
// XOR swizzle, double-buffer (round-8/12 structure -- best measured).
// ---------------------------------------------------------------------------
#define GSTAGE(K0, NB) do {                                                    \
    _Pragma("unroll")                                                          \
    for (int j = 0; j < 4; ++j) {                                              \
      const int chunk = j * 256 + tid;                                         \
      const int rr = chunk >> 3;                                               \
      const int cG = ((chunk & 7) << 4) ^ ((rr & 7) << 4);                     \
      gload16(Ab + ((size_t)(m0 + rr) * K + (K0)) * 2 + cG,                    \
              (char*)&As[NB][0][0] + chunk * 16);                              \
      gload16(Wb + ((size_t)(n0 + rr) * K + (K0)) * 2 + cG,                    \
              (char*)&Bs[NB][0][0] + chunk * 16);                              \
    }                                                                          \
  } while (0)

template<int MODE>
__global__ __launch_bounds__(256)
void gemm_bt(const bf16* __restrict__ A, const bf16* __restrict__ W,
             const float* __restrict__ bias, void* __restrict__ Cout,
             int M, int N, int K)
{
  __shared__ __align__(16) bf16 As[2][128][64];
  __shared__ __align__(16) bf16 Bs[2][128][64];
  const int tid  = threadIdx.x;
  const int lane = tid & 63, wid = tid >> 6;
  const int l15  = lane & 15, lg = lane >> 4;
  const int L  = (blockIdx.x & 7) * 64 + (blockIdx.x >> 3);
  const int m0 = (L >> 3) * 128, n0 = (L & 7) * 128;
  const int wm = wid >> 1, wn = wid & 1;
  const char* Ab = (const char*)A;
  const char* Wb = (const char*)W;

  f32x4 acc[4][4] = {};

  GSTAGE(0, 0);
  asm volatile("s_waitcnt vmcnt(0)" ::: "memory");
  __syncthreads();

  int cur = 0;
  const int NT = K >> 6;
  for (int t = 0; t < NT; ++t) {
    if (t + 1 < NT) GSTAGE((t + 1) << 6, cur ^ 1);

    bf16x8 af[4][2], bfr[4][2];
    #pragma unroll
    for (int i = 0; i < 4; ++i) {
      const int ra = wm * 64 + i * 16 + l15;
      const int rb = wn * 64 + i * 16 + l15;
      #pragma unroll
      for (int s = 0; s < 2; ++s) {
        const int co = (s * 64 + lg * 16);
        af[i][s]  = *reinterpret_cast<const bf16x8*>(
            (const char*)&As[cur][0][0] + ra * 128 + (co ^ ((ra & 7) << 4)));
        bfr[i][s] = *reinterpret_cast<const bf16x8*>(
            (const char*)&Bs[cur][0][0] + rb * 128 + (co ^ ((rb & 7) << 4)));
      }
    }
    __builtin_amdgcn_s_setprio(1);
    #pragma unroll
    for (int s = 0; s < 2; ++s)
      #pragma unroll
      for (int mi = 0; mi < 4; ++mi)
        #pragma unroll
        for (int ni = 0; ni < 4; ++ni)
          acc[mi][ni] = __builtin_amdgcn_mfma_f32_16x16x32_bf16(af[mi][s], bfr[ni][s], acc[mi][ni], 0, 0, 0);
    __builtin_amdgcn_s_setprio(0);

    asm volatile("s_waitcnt vmcnt(0)" ::: "memory");
    __syncthreads();
    cur ^= 1;
  }

  // epilogue: C row = lg*4 + reg, col = l15 within each 16x16 fragment
  #pragma unroll
  for (int ni = 0; ni < 4; ++ni) {
    const int col = n0 + wn * 64 + ni * 16 + l15;
    const float bi = bias[col];
    #pragma unroll
    for (int mi = 0; mi < 4; ++mi) {
      const int row0 = m0 + wm * 64 + mi * 16 + lg * 4;
      if (MODE == 0) {
        bf16* out = (bf16*)Cout;
        #pragma unroll
        for (int r = 0; r < 4; ++r)
          out[(size_t)(row0 + r) * N + col] = (bf16)(acc[mi][ni][r] + bi);
      } else if (MODE == 1) {
        bf16* out = (bf16*)Cout;
        bf16x4 vv;
        #pragma unroll
        for (int r = 0; r < 4; ++r) vv[r] = (bf16)(acc[mi][ni][r] + bi);
        const int seq = row0 & (S_LEN - 1);
        const int t6  = seq & 63;
        const int p0  = (seq & ~63) + ((t6 >> 5) << 5) + (((t6 >> 2) & 3) << 3)
                      + (((t6 >> 4) & 1) << 2);
        *reinterpret_cast<bf16x4*>(
            &out[((size_t)(row0 >> 11) * DIM + col) * S_LEN + p0]) = vv;
      } else if (MODE == 3) {
        bf16* out = (bf16*)Cout;
        #pragma unroll
        for (int r = 0; r < 4; ++r)
          out[(size_t)(row0 + r) * N + col] = (bf16)((acc[mi][ni][r] + bi) * QSCALE);
      } else {
        float* out = (float*)Cout;
        #pragma unroll
        for (int r = 0; r < 4; ++r)
          out[(size_t)(row0 + r) * N + col] = acc[mi][ni][r] + bi;
      }
    }
  }
}

// ---------------------------------------------------------------------------
// Flash attention (round-12 best): static-max softmax, prescaled Q, P in
// registers via cvt_pk + k-permuted V, hoisted addresses, packed-AND mask,
// double-buffered K/V via global_load_lds + XOR swizzle, XCD-chunked grid.
// ---------------------------------------------------------------------------
__global__ __launch_bounds__(512, 4)
void attn_fwd(const bf16* __restrict__ Qb, const bf16* __restrict__ Kb,
              const bf16* __restrict__ Vt, const u64* __restrict__ mbits,
              bf16* __restrict__ ctx)
{
  __shared__ __align__(16) bf16 Kbuf[2][64][64];
  __shared__ __align__(16) bf16 Vbuf[2][64][64];

  const int tid  = threadIdx.x;
  const int lane = tid & 63;
  const int l15  = lane & 15, lg = lane >> 4;
  const int L  = (blockIdx.x & 7) * 64 + (blockIdx.x >> 3);
  const int qi = L & 7;
  const int hb = L >> 3;
  const int h  = hb & 15, b = hb >> 4;
  const int w  = tid >> 6;
  const int qbase = qi * 256 + w * 32;

  const int rr_s = tid >> 3;
  const int cG_s = ((tid & 7) << 4) ^ ((rr_s & 7) << 4);
  const char* gk = (const char*)Kb + ((size_t)(b * S_LEN + rr_s) * DIM + h * DK) * 2 + cG_s;
  const char* gv = (const char*)Vt + ((size_t)b * DIM + h * DK + rr_s) * (S_LEN * 2) + cG_s;
  char* lK = (char*)&Kbuf[0][0][0] + tid * 16;
  char* lV = (char*)&Vbuf[0][0][0] + tid * 16;

  const unsigned xo  = (l15 & 7) << 4;
  const unsigned ko0 = l15 * 128 + ((lg * 16) ^ xo);
  const unsigned ko1 = l15 * 128 + (((64 + lg * 16)) ^ xo);
  const char* KB = (const char*)&Kbuf[0][0][0];
  const char* VB = (const char*)&Vbuf[0][0][0];

  bf16x8 qf[2][2];
  #pragma unroll
  for (int qg = 0; qg < 2; ++qg) {
    const size_t qrow = (size_t)b * S_LEN + qbase + qg * 16 + l15;
    #pragma unroll
    for (int s = 0; s < 2; ++s)
      qf[qg][s] = *reinterpret_cast<const bf16x8*>(&Qb[qrow * DIM + h * DK + s * 32 + lg * 8]);
  }

  bf16x8 onesf;
  #pragma unroll
  for (int j = 0; j < 8; ++j) onesf[j] = (bf16)1.0f;

  union pqu { unsigned u[8]; bf16x8 frag[2]; };

  f32x4 o[2][4] = {};
  f32x4 o_l[2] = {};
  const u64* mp0 = mbits + ((size_t)b * S_LEN + qbase + l15) * (S_LEN / 64);
  const u64* mp1 = mp0 + (size_t)16 * (S_LEN / 64);

  gload16(gk, lK);  gload16(gv, lV);
  gk += 64 * DIM * 2;  gv += 64 * 2;
  u64 mbc[2] = { mp0[0], mp1[0] };
  mp0++; mp1++;

  const int NT = S_LEN / 64;   // 32
  for (int t = 0; t < NT; ++t) {
    asm volatile("s_waitcnt vmcnt(0)" ::: "memory");
    __syncthreads();

    u64 mbn[2] = {0, 0};
    if (t + 1 < NT) {
      mbn[0] = *mp0++;
      mbn[1] = *mp1++;
      const unsigned nb = ((t + 1) & 1) << 13;
      gload16(gk, lK + nb);
      gload16(gv, lV + nb);
      gk += 64 * DIM * 2;
      gv += 64 * 2;
    }

    const unsigned tb = (t & 1) << 13;

    f32x4 sc[2][4] = {};
    __builtin_amdgcn_s_setprio(1);
    #pragma unroll
    for (int s = 0; s < 2; ++s) {
      const char* kp = KB + tb + (s ? ko1 : ko0);
      #pragma unroll
      for (int nf = 0; nf < 4; ++nf) {
        bf16x8 kf = *reinterpret_cast<const bf16x8*>(kp + nf * 2048);
        sc[0][nf] = __builtin_amdgcn_mfma_f32_16x16x32_bf16(kf, qf[0][s], sc[0][nf], 0, 0, 0);
        sc[1][nf] = __builtin_amdgcn_mfma_f32_16x16x32_bf16(kf, qf[1][s], sc[1][nf], 0, 0, 0);
      }
    }
    __builtin_amdgcn_s_setprio(0);

    pqu W[2];
    #pragma unroll
    for (int qg = 0; qg < 2; ++qg) {
      #pragma unroll
      for (int nf = 0; nf < 4; ++nf) {
        const unsigned mm = (unsigned)(mbc[qg] >> (nf * 16 + lg * 4));
        float e0 = exp2fast(sc[qg][nf][0]);
        float e1 = exp2fast(sc[qg][nf][1]);
        float e2 = exp2fast(sc[qg][nf][2]);
        float e3 = exp2fast(sc[qg][nf][3]);
        const unsigned m01 = ((unsigned)(((int)(mm << 31)) >> 31) & 0x0000FFFFu)
                           | ((unsigned)(((int)(mm << 30)) >> 31) & 0xFFFF0000u);
        const unsigned m23 = ((unsigned)(((int)(mm << 29)) >> 31) & 0x0000FFFFu)
                           | ((unsigned)(((int)(mm << 28)) >> 31) & 0xFFFF0000u);
        W[qg].u[nf * 2 + 0] = cvt_pk_bf16(e0, e1) & m01;
        W[qg].u[nf * 2 + 1] = cvt_pk_bf16(e2, e3) & m23;
      }
    }

    __builtin_amdgcn_s_setprio(1);
    #pragma unroll
    for (int s = 0; s < 2; ++s) {
      const char* vp = VB + tb + (s ? ko1 : ko0);
      #pragma unroll
      for (int nf = 0; nf < 4; ++nf) {
        bf16x8 vf = *reinterpret_cast<const bf16x8*>(vp + nf * 2048);
        o[0][nf] = __builtin_amdgcn_mfma_f32_16x16x32_bf16(W[0].frag[s], vf, o[0][nf], 0, 0, 0);
        o[1][nf] = __builtin_amdgcn_mfma_f32_16x16x32_bf16(W[1].frag[s], vf, o[1][nf], 0, 0, 0);
      }
      o_l[0] = __builtin_amdgcn_mfma_f32_16x16x32_bf16(W[0].frag[s], onesf, o_l[0], 0, 0, 0);
      o_l[1] = __builtin_amdgcn_mfma_f32_16x16x32_bf16(W[1].frag[s], onesf, o_l[1], 0, 0, 0);
    }
    __builtin_amdgcn_s_setprio(0);

    mbc[0] = mbn[0]; mbc[1] = mbn[1];
  }

  #pragma unroll
  for (int qg = 0; qg < 2; ++qg) {
    float lf[4];
    #pragma unroll
    for (int r = 0; r < 4; ++r) lf[r] = 1.0f / o_l[qg][r];
    #pragma unroll
    for (int nf = 0; nf < 4; ++nf)
      #pragma unroll
      for (int r = 0; r < 4; ++r) {
        const int q = qbase + qg * 16 + lg * 4 + r;
        ctx[((size_t)b * S_LEN + q) * DIM + h * DK + nf * 16 + l15] = (bf16)(o[qg][nf][r] * lf[r]);
      }
  }
}

// ---------------------------------------------------------------------------
extern "C" void kernel_launch(void* const* d_in, const int* in_sizes, int n_in,
                              void* d_out, int out_size, void* d_ws, size_t ws_size,
                              hipStream_t stream)
{
  const float* q    = (const float*)d_in[0];
  const float* k    = (const float*)d_in[1];
  const float* v    = (const float*)d_in[2];
  const int*   mask = (const int*)  d_in[3];
  const float* Wq   = (const float*)d_in[4];
  const float* bq   = (const float*)d_in[5];
  const float* Wk   = (const float*)d_in[6];
  const float* bk   = (const float*)d_in[7];
  const float* Wv   = (const float*)d_in[8];
  const float* bv   = (const float*)d_in[9];
  const float* Wo   = (const float*)d_in[10];
  const float* bo   = (const float*)d_in[11];
  float* out = (float*)d_out;

  const size_t NE = (size_t)BATCH * S_LEN * DIM;  // 8.39M elements
  const size_t NW = (size_t)DIM * DIM;            // 1.05M elements
  bf16* qB  = (bf16*)d_ws;                        // bf16 copies of inputs
  bf16* kB  = qB + NE;
  bf16* vB  = kB + NE;
  bf16* Qb  = vB + NE;                            // projected Q,K,V
  bf16* Kb  = Qb + NE;
  bf16* Vt  = Kb + NE;
  bf16* WqB = Vt + NE;                            // bf16 weights
  bf16* WkB = WqB + NW;
  bf16* WvB = WkB + NW;
  bf16* WoB = WvB + NW;
  u64*  bits = (u64*)(WoB + NW);                  // 2 MB
  bf16* ctx = qB;                                 // reuse: qB dead after QKV GEMMs

  const int M = BATCH * S_LEN;  // 8192

  pack_mask<<<(BATCH * S_LEN * (S_LEN / 64)) / 4, 256, 0, stream>>>(mask, bits);
  conv_all<<<dim3(4096, 4), 256, 0, stream>>>(q, k, v, Wq, Wk, Wv, Wo,
                                              qB, kB, vB, WqB, WkB, WvB, WoB);

  gemm_bt<3><<<512, 256, 0, stream>>>(qB, WqB, bq, Qb, M, DIM, DIM);   // Q prescaled
  gemm_bt<0><<<512, 256, 0, stream>>>(kB, WkB, bk, Kb, M, DIM, DIM);
  gemm_bt<1><<<512, 256, 0, stream>>>(vB, WvB, bv, Vt, M, DIM, DIM);   // V k-permuted

  attn_fwd<<<512, 512, 0, stream>>>(Qb, Kb, Vt, bits, ctx);

  gemm_bt<2><<<512, 256, 0, stream>>>(ctx, WoB, bo, out, M, DIM, DIM);
}

// Round 15
// 231.348 us; speedup vs baseline: 1.1650x; 1.0294x over previous
//
#include <hip/hip_runtime.h>
#include <math.h>

#define S_LEN 2048
#define DIM   1024
#define HEADS 16
#define DK    64
#define BATCH 4

typedef __bf16 bf16;
typedef bf16  bf16x8 __attribute__((ext_vector_type(8)));
typedef bf16  bf16x4 __attribute__((ext_vector_type(4)));
typedef float f32x4  __attribute__((ext_vector_type(4)));
typedef unsigned long long u64;

#define QSCALE (0.125f * 1.44269504088896f)   // 1/sqrt(dk) * log2(e)

__device__ __forceinline__ void gload16(const void* g, void* l) {
  __builtin_amdgcn_global_load_lds((const __attribute__((address_space(1))) void*)g,
                                   (__attribute__((address_space(3))) void*)l, 16, 0, 0);
}
__device__ __forceinline__ float exp2fast(float x) {
  float r; asm("v_exp_f32 %0, %1" : "=v"(r) : "v"(x)); return r;
}
__device__ __forceinline__ unsigned cvt_pk_bf16(float a, float b) {
  unsigned r; asm("v_cvt_pk_bf16_f32 %0, %1, %2" : "=v"(r) : "v"(a), "v"(b)); return r;
}

// ---------------------------------------------------------------------------
// Combined BW-bound pass: f32->bf16 conversion of all 7 tensors + mask
// bitpack, one dispatch. All blocks are short streaming blocks (unlike
// round-13's failed fusion, where 35us serial pack blocks starved a compute
// kernel). y<3: q/k/v. y==3: weights. y==4: mask bitpack (64 u64 words/blk).
// ---------------------------------------------------------------------------
__global__ __launch_bounds__(256)
void conv_pack(const float* __restrict__ q, const float* __restrict__ k,
               const float* __restrict__ v,
               const float* __restrict__ Wq, const float* __restrict__ Wk,
               const float* __restrict__ Wv, const float* __restrict__ Wo,
               bf16* __restrict__ qB, bf16* __restrict__ kB, bf16* __restrict__ vB,
               bf16* __restrict__ WqB, bf16* __restrict__ WkB,
               bf16* __restrict__ WvB, bf16* __restrict__ WoB,
               const int* __restrict__ mask, u64* __restrict__ bits)
{
  const int y = blockIdx.y;
  if (y == 4) {
    // mask bitpack: 4096 blocks x 64 words (16 ballots/wave)
    const int lane = threadIdx.x & 63;
    const size_t w0 = (size_t)blockIdx.x * 64 + (threadIdx.x >> 6);
    #pragma unroll
    for (int it = 0; it < 16; ++it) {
      const size_t w = w0 + it * 4;
      const u64 bb = __ballot(mask[w * 64 + lane] != 0);
      if (lane == 0) bits[w] = bb;
    }
    return;
  }
  const float* in;
  bf16* out;
  size_t idx;
  if (y < 3) {
    in  = (y == 0) ? q  : (y == 1) ? k  : v;
    out = (y == 0) ? qB : (y == 1) ? kB : vB;
    idx = ((size_t)blockIdx.x * 256 + threadIdx.x) * 8;
  } else {
    if (blockIdx.x >= 2048) return;
    const int wsel = blockIdx.x >> 9, inner = blockIdx.x & 511;
    in  = (wsel == 0) ? Wq  : (wsel == 1) ? Wk  : (wsel == 2) ? Wv  : Wo;
    out = (wsel == 0) ? WqB : (wsel == 1) ? WkB : (wsel == 2) ? WvB : WoB;
    idx = ((size_t)inner * 256 + threadIdx.x) * 8;
  }
  float4 a = *reinterpret_cast<const float4*>(&in[idx]);
  float4 b = *reinterpret_cast<const float4*>(&in[idx + 4]);
  bf16x8 r;
  r[0] = (bf16)a.x; r[1] = (bf16)a.y; r[2] = (bf16)a.z; r[3] = (bf16)a.w;
  r[4] = (bf16)b.x; r[5] = (bf16)b.y; r[6] = (bf16)b.z; r[7] = (bf16)b.w;
  *reinterpret_cast<bf16x8*>(&out[idx]) = r;
}

// ---------------------------------------------------------------------------
// Merged QKV projection GEMMs: one 1536-block dispatch, which = bx>>9
// (0:Q prescaled, 1:K plain, 2:V transposed+k-permuted). Same XCD-chunked
// decode on inner = bx&511. One block supply -> one tail instead of three,
// no launch gaps between Q/K/V. Mainloop = round-8 structure (best measured).
// ---------------------------------------------------------------------------
#define GSTAGE(K0, NB) do {                                                    \
    _Pragma("unroll")                                                          \
    for (int j = 0; j < 4; ++j) {                                              \
      const int chunk = j * 256 + tid;                                         \
      const int rr = chunk >> 3;                                               \
      const int cG = ((chunk & 7) << 4) ^ ((rr & 7) << 4);                     \
      gload16(Ab + ((size_t)(m0 + rr) * 1024 + (K0)) * 2 + cG,                 \
              (char*)&As[NB][0][0] + chunk * 16);                              \
      gload16(Wb + ((size_t)(n0 + rr) * 1024 + (K0)) * 2 + cG,                 \
              (char*)&Bs[NB][0][0] + chunk * 16);                              \
    }                                                                          \
  } while (0)

#define GEMM_MAINLOOP()                                                        \
  f32x4 acc[4][4] = {};                                                        \
  GSTAGE(0, 0);                                                                \
  asm volatile("s_waitcnt vmcnt(0)" ::: "memory");                             \
  __syncthreads();                                                             \
  int cur = 0;                                                                 \
  for (int t = 0; t < 16; ++t) {                                               \
    if (t + 1 < 16) GSTAGE((t + 1) << 6, cur ^ 1);                             \
    bf16x8 af[4][2], bfr[4][2];                                                \
    _Pragma("unroll")                                                          \
    for (int i = 0; i < 4; ++i) {                                              \
      const int ra = wm * 64 + i * 16 + l15;                                   \
      const int rb = wn * 64 + i * 16 + l15;                                   \
      _Pragma("unroll")                                                        \
      for (int s = 0; s < 2; ++s) {                                            \
        const int co = (s * 64 + lg * 16);                                     \
        af[i][s]  = *reinterpret_cast<const bf16x8*>(                          \
            (const char*)&As[cur][0][0] + ra * 128 + (co ^ ((ra & 7) << 4)));  \
        bfr[i][s] = *reinterpret_cast<const bf16x8*>(                          \
            (const char*)&Bs[cur][0][0] + rb * 128 + (co ^ ((rb & 7) << 4)));  \
      }                                                                        \
    }                                                                          \
    __builtin_amdgcn_s_setprio(1);                                             \
    _Pragma("unroll")                                                          \
    for (int s = 0; s < 2; ++s)                                                \
      _Pragma("unroll")                                                        \
      for (int mi = 0; mi < 4; ++mi)                                           \
        _Pragma("unroll")                                                      \
        for (int ni = 0; ni < 4; ++ni)                                         \
          acc[mi][ni] = __builtin_amdgcn_mfma_f32_16x16x32_bf16(af[mi][s], bfr[ni][s], acc[mi][ni], 0, 0, 0); \
    __builtin_amdgcn_s_setprio(0);                                             \
    asm volatile("s_waitcnt vmcnt(0)" ::: "memory");                           \
    __syncthreads();                                                           \
    cur ^= 1;                                                                  \
  }

__global__ __launch_bounds__(256)
void gemm_qkv(const bf16* __restrict__ qB, const bf16* __restrict__ kB,
              const bf16* __restrict__ vB,
              const bf16* __restrict__ WqB, const bf16* __restrict__ WkB,
              const bf16* __restrict__ WvB,
              const float* __restrict__ bq, const float* __restrict__ bk,
              const float* __restrict__ bv,
              bf16* __restrict__ Qb, bf16* __restrict__ Kb,
              bf16* __restrict__ Vt)
{
  __shared__ __align__(16) bf16 As[2][128][64];
  __shared__ __align__(16) bf16 Bs[2][128][64];
  const int tid = threadIdx.x;
  const int which = blockIdx.x >> 9;            // 0:Q 1:K 2:V (block-uniform)
  const int inner = blockIdx.x & 511;
  const bf16* A     = (which == 0) ? qB  : (which == 1) ? kB  : vB;
  const bf16* W     = (which == 0) ? WqB : (which == 1) ? WkB : WvB;
  const float* bias = (which == 0) ? bq  : (which == 1) ? bk  : bv;

  const int lane = tid & 63, wid = tid >> 6;
  const int l15  = lane & 15, lg = lane >> 4;
  const int L  = (inner & 7) * 64 + (inner >> 3);   // XCD-chunked
  const int m0 = (L >> 3) * 128, n0 = (L & 7) * 128;
  const int wm = wid >> 1, wn = wid & 1;
  const char* Ab = (const char*)A;
  const char* Wb = (const char*)W;

  GEMM_MAINLOOP();

  #pragma unroll
  for (int ni = 0; ni < 4; ++ni) {
    const int col = n0 + wn * 64 + ni * 16 + l15;
    const float bi = bias[col];
    #pragma unroll
    for (int mi = 0; mi < 4; ++mi) {
      const int row0 = m0 + wm * 64 + mi * 16 + lg * 4;
      if (which == 0) {
        #pragma unroll
        for (int r = 0; r < 4; ++r)
          Qb[(size_t)(row0 + r) * DIM + col] = (bf16)((acc[mi][ni][r] + bi) * QSCALE);
      } else if (which == 1) {
        #pragma unroll
        for (int r = 0; r < 4; ++r)
          Kb[(size_t)(row0 + r) * DIM + col] = (bf16)(acc[mi][ni][r] + bi);
      } else {
        bf16x4 vv;
        #pragma unroll
        for (int r = 0; r < 4; ++r) vv[r] = (bf16)(acc[mi][ni][r] + bi);
        const int seq = row0 & (S_LEN - 1);
        const int t6  = seq & 63;
        const int p0  = (seq & ~63) + ((t6 >> 5) << 5) + (((t6 >> 2) & 3) << 3)
                      + (((t6 >> 4) & 1) << 2);
        *reinterpret_cast<bf16x4*>(
            &Vt[((size_t)(row0 >> 11) * DIM + col) * S_LEN + p0]) = vv;
      }
    }
  }
}

// ---------------------------------------------------------------------------
// O-projection GEMM (f32 out), standalone.
// ---------------------------------------------------------------------------
__global__ __launch_bounds__(256)
void gemm_out(const bf16* __restrict__ A, const bf16* __restrict__ W,
              const float* __restrict__ bias, float* __restrict__ out)
{
  __shared__ __align__(16) bf16 As[2][128][64];
  __shared__ __align__(16) bf16 Bs[2][128][64];
  const int tid  = threadIdx.x;
  const int lane = tid & 63, wid = tid >> 6;
  const int l15  = lane & 15, lg = lane >> 4;
  const int L  = (blockIdx.x & 7) * 64 + (blockIdx.x >> 3);
  const int m0 = (L >> 3) * 128, n0 = (L & 7) * 128;
  const int wm = wid >> 1, wn = wid & 1;
  const char* Ab = (const char*)A;
  const char* Wb = (const char*)W;

  GEMM_MAINLOOP();

  #pragma unroll
  for (int ni = 0; ni < 4; ++ni) {
    const int col = n0 + wn * 64 + ni * 16 + l15;
    const float bi = bias[col];
    #pragma unroll
    for (int mi = 0; mi < 4; ++mi) {
      const int row0 = m0 + wm * 64 + mi * 16 + lg * 4;
      #pragma unroll
      for (int r = 0; r < 4; ++r)
        out[(size_t)(row0 + r) * DIM + col] = acc[mi][ni][r] + bi;
    }
  }
}

// ---------------------------------------------------------------------------
// Flash attention (round-12 best, unchanged): static-max softmax, prescaled
// Q, P in registers via cvt_pk + k-permuted V, hoisted addresses, packed-AND
// mask, double-buffered K/V via global_load_lds + XOR swizzle, XCD-chunked.
// ---------------------------------------------------------------------------
__global__ __launch_bounds__(512, 4)
void attn_fwd(const bf16* __restrict__ Qb, const bf16* __restrict__ Kb,
              const bf16* __restrict__ Vt, const u64* __restrict__ mbits,
              bf16* __restrict__ ctx)
{
  __shared__ __align__(16) bf16 Kbuf[2][64][64];
  __shared__ __align__(16) bf16 Vbuf[2][64][64];

  const int tid  = threadIdx.x;
  const int lane = tid & 63;
  const int l15  = lane & 15, lg = lane >> 4;
  const int L  = (blockIdx.x & 7) * 64 + (blockIdx.x >> 3);
  const int qi = L & 7;
  const int hb = L >> 3;
  const int h  = hb & 15, b = hb >> 4;
  const int w  = tid >> 6;
  const int qbase = qi * 256 + w * 32;

  const int rr_s = tid >> 3;
  const int cG_s = ((tid & 7) << 4) ^ ((rr_s & 7) << 4);
  const char* gk = (const char*)Kb + ((size_t)(b * S_LEN + rr_s) * DIM + h * DK) * 2 + cG_s;
  const char* gv = (const char*)Vt + ((size_t)b * DIM + h * DK + rr_s) * (S_LEN * 2) + cG_s;
  char* lK = (char*)&Kbuf[0][0][0] + tid * 16;
  char* lV = (char*)&Vbuf[0][0][0] + tid * 16;

  const unsigned xo  = (l15 & 7) << 4;
  const unsigned ko0 = l15 * 128 + ((lg * 16) ^ xo);
  const unsigned ko1 = l15 * 128 + (((64 + lg * 16)) ^ xo);
  const char* KB = (const char*)&Kbuf[0][0][0];
  const char* VB = (const char*)&Vbuf[0][0][0];

  bf16x8 qf[2][2];
  #pragma unroll
  for (int qg = 0; qg < 2; ++qg) {
    const size_t qrow = (size_t)b * S_LEN + qbase + qg * 16 + l15;
    #pragma unroll
    for (int s = 0; s < 2; ++s)
      qf[qg][s] = *reinterpret_cast<const bf16x8*>(&Qb[qrow * DIM + h * DK + s * 32 + lg * 8]);
  }

  bf16x8 onesf;
  #pragma unroll
  for (int j = 0; j < 8; ++j) onesf[j] = (bf16)1.0f;

  union pqu { unsigned u[8]; bf16x8 frag[2]; };

  f32x4 o[2][4] = {};
  f32x4 o_l[2] = {};
  const u64* mp0 = mbits + ((size_t)b * S_LEN + qbase + l15) * (S_LEN / 64);
  const u64* mp1 = mp0 + (size_t)16 * (S_LEN / 64);

  gload16(gk, lK);  gload16(gv, lV);
  gk += 64 * DIM * 2;  gv += 64 * 2;
  u64 mbc[2] = { mp0[0], mp1[0] };
  mp0++; mp1++;

  const int NT = S_LEN / 64;   // 32
  for (int t = 0; t < NT; ++t) {
    asm volatile("s_waitcnt vmcnt(0)" ::: "memory");
    __syncthreads();

    u64 mbn[2] = {0, 0};
    if (t + 1 < NT) {
      mbn[0] = *mp0++;
      mbn[1] = *mp1++;
      const unsigned nb = ((t + 1) & 1) << 13;
      gload16(gk, lK + nb);
      gload16(gv, lV + nb);
      gk += 64 * DIM * 2;
      gv += 64 * 2;
    }

    const unsigned tb = (t & 1) << 13;

    f32x4 sc[2][4] = {};
    __builtin_amdgcn_s_setprio(1);
    #pragma unroll
    for (int s = 0; s < 2; ++s) {
      const char* kp = KB + tb + (s ? ko1 : ko0);
      #pragma unroll
      for (int nf = 0; nf < 4; ++nf) {
        bf16x8 kf = *reinterpret_cast<const bf16x8*>(kp + nf * 2048);
        sc[0][nf] = __builtin_amdgcn_mfma_f32_16x16x32_bf16(kf, qf[0][s], sc[0][nf], 0, 0, 0);
        sc[1][nf] = __builtin_amdgcn_mfma_f32_16x16x32_bf16(kf, qf[1][s], sc[1][nf], 0, 0, 0);
      }
    }
    __builtin_amdgcn_s_setprio(0);

    pqu W[2];
    #pragma unroll
    for (int qg = 0; qg < 2; ++qg) {
      #pragma unroll
      for (int nf = 0; nf < 4; ++nf) {
        const unsigned mm = (unsigned)(mbc[qg] >> (nf * 16 + lg * 4));
        float e0 = exp2fast(sc[qg][nf][0]);
        float e1 = exp2fast(sc[qg][nf][1]);
        float e2 = exp2fast(sc[qg][nf][2]);
        float e3 = exp2fast(sc[qg][nf][3]);
        const unsigned m01 = ((unsigned)(((int)(mm << 31)) >> 31) & 0x0000FFFFu)
                           | ((unsigned)(((int)(mm << 30)) >> 31) & 0xFFFF0000u);
        const unsigned m23 = ((unsigned)(((int)(mm << 29)) >> 31) & 0x0000FFFFu)
                           | ((unsigned)(((int)(mm << 28)) >> 31) & 0xFFFF0000u);
        W[qg].u[nf * 2 + 0] = cvt_pk_bf16(e0, e1) & m01;
        W[qg].u[nf * 2 + 1] = cvt_pk_bf16(e2, e3) & m23;
      }
    }

    __builtin_amdgcn_s_setprio(1);
    #pragma unroll
    for (int s = 0; s < 2; ++s) {
      const char* vp = VB + tb + (s ? ko1 : ko0);
      #pragma unroll
      for (int nf = 0; nf < 4; ++nf) {
        bf16x8 vf = *reinterpret_cast<const bf16x8*>(vp + nf * 2048);
        o[0][nf] = __builtin_amdgcn_mfma_f32_16x16x32_bf16(W[0].frag[s], vf, o[0][nf], 0, 0, 0);
        o[1][nf] = __builtin_amdgcn_mfma_f32_16x16x32_bf16(W[1].frag[s], vf, o[1][nf], 0, 0, 0);
      }
      o_l[0] = __builtin_amdgcn_mfma_f32_16x16x32_bf16(W[0].frag[s], onesf, o_l[0], 0, 0, 0);
      o_l[1] = __builtin_amdgcn_mfma_f32_16x16x32_bf16(W[1].frag[s], onesf, o_l[1], 0, 0, 0);
    }
    __builtin_amdgcn_s_setprio(0);

    mbc[0] = mbn[0]; mbc[1] = mbn[1];
  }

  #pragma unroll
  for (int qg = 0; qg < 2; ++qg) {
    float lf[4];
    #pragma unroll
    for (int r = 0; r < 4; ++r) lf[r] = 1.0f / o_l[qg][r];
    #pragma unroll
    for (int nf = 0; nf < 4; ++nf)
      #pragma unroll
      for (int r = 0; r < 4; ++r) {
        const int q = qbase + qg * 16 + lg * 4 + r;
        ctx[((size_t)b * S_LEN + q) * DIM + h * DK + nf * 16 + l15] = (bf16)(o[qg][nf][r] * lf[r]);
      }
  }
}

// ---------------------------------------------------------------------------
extern "C" void kernel_launch(void* const* d_in, const int* in_sizes, int n_in,
                              void* d_out, int out_size, void* d_ws, size_t ws_size,
                              hipStream_t stream)
{
  const float* q    = (const float*)d_in[0];
  const float* k    = (const float*)d_in[1];
  const float* v    = (const float*)d_in[2];
  const int*   mask = (const int*)  d_in[3];
  const float* Wq   = (const float*)d_in[4];
  const float* bq   = (const float*)d_in[5];
  const float* Wk   = (const float*)d_in[6];
  const float* bk   = (const float*)d_in[7];
  const float* Wv   = (const float*)d_in[8];
  const float* bv   = (const float*)d_in[9];
  const float* Wo   = (const float*)d_in[10];
  const float* bo   = (const float*)d_in[11];
  float* out = (float*)d_out;

  const size_t NE = (size_t)BATCH * S_LEN * DIM;  // 8.39M elements
  const size_t NW = (size_t)DIM * DIM;            // 1.05M elements
  bf16* qB  = (bf16*)d_ws;                        // bf16 copies of inputs
  bf16* kB  = qB + NE;
  bf16* vB  = kB + NE;
  bf16* Qb  = vB + NE;                            // projected Q,K,V
  bf16* Kb  = Qb + NE;
  bf16* Vt  = Kb + NE;
  bf16* WqB = Vt + NE;                            // bf16 weights
  bf16* WkB = WqB + NW;
  bf16* WvB = WkB + NW;
  bf16* WoB = WvB + NW;
  u64*  bits = (u64*)(WoB + NW);                  // 2 MB
  bf16* ctx = qB;                                 // reuse: qB dead after QKV GEMMs

  conv_pack<<<dim3(4096, 5), 256, 0, stream>>>(q, k, v, Wq, Wk, Wv, Wo,
                                               qB, kB, vB, WqB, WkB, WvB, WoB,
                                               mask, bits);

  gemm_qkv<<<1536, 256, 0, stream>>>(qB, kB, vB, WqB, WkB, WvB,
                                     bq, bk, bv, Qb, Kb, Vt);

  attn_fwd<<<512, 512, 0, stream>>>(Qb, Kb, Vt, bits, ctx);

  gemm_out<<<512, 256, 0, stream>>>(ctx, WoB, bo, out);
}

// Round 16
// 223.386 us; speedup vs baseline: 1.2065x; 1.0356x over previous
//
#include <hip/hip_runtime.h>
#include <math.h>

#define S_LEN 2048
#define DIM   1024
#define HEADS 16
#define DK    64
#define BATCH 4

typedef __bf16 bf16;
typedef bf16  bf16x8 __attribute__((ext_vector_type(8)));
typedef bf16  bf16x4 __attribute__((ext_vector_type(4)));
typedef float f32x4  __attribute__((ext_vector_type(4)));
typedef unsigned long long u64;

#define QSCALE (0.125f * 1.44269504088896f)   // 1/sqrt(dk) * log2(e)

__device__ __forceinline__ void gload16(const void* g, void* l) {
  __builtin_amdgcn_global_load_lds((const __attribute__((address_space(1))) void*)g,
                                   (__attribute__((address_space(3))) void*)l, 16, 0, 0);
}
__device__ __forceinline__ float exp2fast(float x) {
  float r; asm("v_exp_f32 %0, %1" : "=v"(r) : "v"(x)); return r;
}
__device__ __forceinline__ unsigned cvt_pk_bf16(float a, float b) {
  unsigned r; asm("v_cvt_pk_bf16_f32 %0, %1, %2" : "=v"(r) : "v"(a), "v"(b)); return r;
}

// ---------------------------------------------------------------------------
// Combined BW-bound pass: f32->bf16 conversion of all 7 tensors + mask
// bitpack, one dispatch (all short streaming blocks).
// ---------------------------------------------------------------------------
__global__ __launch_bounds__(256)
void conv_pack(const float* __restrict__ q, const float* __restrict__ k,
               const float* __restrict__ v,
               const float* __restrict__ Wq, const float* __restrict__ Wk,
               const float* __restrict__ Wv, const float* __restrict__ Wo,
               bf16* __restrict__ qB, bf16* __restrict__ kB, bf16* __restrict__ vB,
               bf16* __restrict__ WqB, bf16* __restrict__ WkB,
               bf16* __restrict__ WvB, bf16* __restrict__ WoB,
               const int* __restrict__ mask, u64* __restrict__ bits)
{
  const int y = blockIdx.y;
  if (y == 4) {
    const int lane = threadIdx.x & 63;
    const size_t w0 = (size_t)blockIdx.x * 64 + (threadIdx.x >> 6);
    #pragma unroll
    for (int it = 0; it < 16; ++it) {
      const size_t w = w0 + it * 4;
      const u64 bb = __ballot(mask[w * 64 + lane] != 0);
      if (lane == 0) bits[w] = bb;
    }
    return;
  }
  const float* in;
  bf16* out;
  size_t idx;
  if (y < 3) {
    in  = (y == 0) ? q  : (y == 1) ? k  : v;
    out = (y == 0) ? qB : (y == 1) ? kB : vB;
    idx = ((size_t)blockIdx.x * 256 + threadIdx.x) * 8;
  } else {
    if (blockIdx.x >= 2048) return;
    const int wsel = blockIdx.x >> 9, inner = blockIdx.x & 511;
    in  = (wsel == 0) ? Wq  : (wsel == 1) ? Wk  : (wsel == 2) ? Wv  : Wo;
    out = (wsel == 0) ? WqB : (wsel == 1) ? WkB : (wsel == 2) ? WvB : WoB;
    idx = ((size_t)inner * 256 + threadIdx.x) * 8;
  }
  float4 a = *reinterpret_cast<const float4*>(&in[idx]);
  float4 b = *reinterpret_cast<const float4*>(&in[idx + 4]);
  bf16x8 r;
  r[0] = (bf16)a.x; r[1] = (bf16)a.y; r[2] = (bf16)a.z; r[3] = (bf16)a.w;
  r[4] = (bf16)b.x; r[5] = (bf16)b.y; r[6] = (bf16)b.z; r[7] = (bf16)b.w;
  *reinterpret_cast<bf16x8*>(&out[idx]) = r;
}

// ---------------------------------------------------------------------------
// Merged QKV projection GEMMs, BK=32, 32 KB LDS -> 4 blocks/CU (vs 2 at
// BK=64): the 1536-block grid now keeps 16 waves/CU over the vmcnt drains.
// LDS row r (128 B, bank-aligned) = [A-row r (64B) | W-row r (64B)], 16B
// blocks XOR-permuted by (r&7) via pre-swizzled global source; read offsets
// fully hoisted (ra&7 == l15&7). One mfma K-step (K=32) per tile.
// which = bx>>9: 0:Q prescaled, 1:K plain, 2:V transposed+k-permuted.
// ---------------------------------------------------------------------------
__global__ __launch_bounds__(256, 4)
void gemm_qkv(const bf16* __restrict__ qB, const bf16* __restrict__ kB,
              const bf16* __restrict__ vB,
              const bf16* __restrict__ WqB, const bf16* __restrict__ WkB,
              const bf16* __restrict__ WvB,
              const float* __restrict__ bq, const float* __restrict__ bk,
              const float* __restrict__ bv,
              bf16* __restrict__ Qb, bf16* __restrict__ Kb,
              bf16* __restrict__ Vt)
{
  __shared__ __align__(16) bf16 AB[2][128][64];   // 32 KB
  const int tid = threadIdx.x;
  const int which = blockIdx.x >> 9;            // 0:Q 1:K 2:V (block-uniform)
  const int inner = blockIdx.x & 511;
  const bf16* A     = (which == 0) ? qB  : (which == 1) ? kB  : vB;
  const bf16* W     = (which == 0) ? WqB : (which == 1) ? WkB : WvB;
  const float* bias = (which == 0) ? bq  : (which == 1) ? bk  : bv;

  const int lane = tid & 63, wid = tid >> 6;
  const int l15  = lane & 15, lg = lane >> 4;
  const int L  = (inner & 7) * 64 + (inner >> 3);   // XCD-chunked
  const int m0 = (L >> 3) * 128, n0 = (L & 7) * 128;
  const int wm = wid >> 1, wn = wid & 1;

  // staging: 4 chunks/thread, running global pointers (advance 64 B per tile)
  const char* src0; const char* src1; const char* src2; const char* src3;
  char* dst0; char* dst1; char* dst2; char* dst3;
  {
    #define MKCH(J, SRC, DST)                                                  \
      { const int c = (J) * 256 + tid;                                         \
        const int r = c >> 3;                                                  \
        const int g = (c & 7) ^ (r & 7);                                       \
        SRC = ((g < 4) ? (const char*)A + (size_t)(m0 + r) * 2048              \
                       : (const char*)W + (size_t)(n0 + r) * 2048) + (g & 3) * 16; \
        DST = (char*)&AB[0][0][0] + c * 16; }
    MKCH(0, src0, dst0) MKCH(1, src1, dst1) MKCH(2, src2, dst2) MKCH(3, src3, dst3)
    #undef MKCH
  }

  gload16(src0, dst0); gload16(src1, dst1); gload16(src2, dst2); gload16(src3, dst3);
  src0 += 64; src1 += 64; src2 += 64; src3 += 64;
  asm volatile("s_waitcnt vmcnt(0)" ::: "memory");
  __syncthreads();

  const unsigned swz  = (l15 & 7) << 4;
  const unsigned aoff = (unsigned)(wm * 64 + l15) * 128 + ((lg * 16) ^ swz);
  const unsigned boff = (unsigned)(wn * 64 + l15) * 128 + ((64 + lg * 16) ^ swz);
  const char* ABB = (const char*)&AB[0][0][0];

  f32x4 acc[4][4] = {};

  for (int t = 0; t < 32; ++t) {
    if (t + 1 < 32) {
      const unsigned nb = ((t + 1) & 1) << 14;
      gload16(src0, dst0 + nb); gload16(src1, dst1 + nb);
      gload16(src2, dst2 + nb); gload16(src3, dst3 + nb);
      src0 += 64; src1 += 64; src2 += 64; src3 += 64;
    }
    const unsigned tb = (t & 1) << 14;

    bf16x8 af[4], bfr[4];
    #pragma unroll
    for (int i = 0; i < 4; ++i) {
      af[i]  = *reinterpret_cast<const bf16x8*>(ABB + tb + aoff + i * 2048);
      bfr[i] = *reinterpret_cast<const bf16x8*>(ABB + tb + boff + i * 2048);
    }
    __builtin_amdgcn_s_setprio(1);
    #pragma unroll
    for (int mi = 0; mi < 4; ++mi)
      #pragma unroll
      for (int ni = 0; ni < 4; ++ni)
        acc[mi][ni] = __builtin_amdgcn_mfma_f32_16x16x32_bf16(af[mi], bfr[ni], acc[mi][ni], 0, 0, 0);
    __builtin_amdgcn_s_setprio(0);

    asm volatile("s_waitcnt vmcnt(0)" ::: "memory");
    __syncthreads();
  }

  #pragma unroll
  for (int ni = 0; ni < 4; ++ni) {
    const int col = n0 + wn * 64 + ni * 16 + l15;
    const float bi = bias[col];
    #pragma unroll
    for (int mi = 0; mi < 4; ++mi) {
      const int row0 = m0 + wm * 64 + mi * 16 + lg * 4;
      if (which == 0) {
        #pragma unroll
        for (int r = 0; r < 4; ++r)
          Qb[(size_t)(row0 + r) * DIM + col] = (bf16)((acc[mi][ni][r] + bi) * QSCALE);
      } else if (which == 1) {
        #pragma unroll
        for (int r = 0; r < 4; ++r)
          Kb[(size_t)(row0 + r) * DIM + col] = (bf16)(acc[mi][ni][r] + bi);
      } else {
        bf16x4 vv;
        #pragma unroll
        for (int r = 0; r < 4; ++r) vv[r] = (bf16)(acc[mi][ni][r] + bi);
        const int seq = row0 & (S_LEN - 1);
        const int t6  = seq & 63;
        const int p0  = (seq & ~63) + ((t6 >> 5) << 5) + (((t6 >> 2) & 3) << 3)
                      + (((t6 >> 4) & 1) << 2);
        *reinterpret_cast<bf16x4*>(
            &Vt[((size_t)(row0 >> 11) * DIM + col) * S_LEN + p0]) = vv;
      }
    }
  }
}

// ---------------------------------------------------------------------------
// O-projection GEMM (f32 out), BK=64 round-8 structure (512-block grid is
// occupancy-capped at 2 blocks/CU anyway, so BK=32 wouldn't help here).
// ---------------------------------------------------------------------------
#define GSTAGE(K0, NB) do {                                                    \
    _Pragma("unroll")                                                          \
    for (int j = 0; j < 4; ++j) {                                              \
      const int chunk = j * 256 + tid;                                         \
      const int rr = chunk >> 3;                                               \
      const int cG = ((chunk & 7) << 4) ^ ((rr & 7) << 4);                     \
      gload16(Ab + ((size_t)(m0 + rr) * 1024 + (K0)) * 2 + cG,                 \
              (char*)&As[NB][0][0] + chunk * 16);                              \
      gload16(Wb + ((size_t)(n0 + rr) * 1024 + (K0)) * 2 + cG,                 \
              (char*)&Bs[NB][0][0] + chunk * 16);                              \
    }                                                                          \
  } while (0)

__global__ __launch_bounds__(256)
void gemm_out(const bf16* __restrict__ A, const bf16* __restrict__ W,
              const float* __restrict__ bias, float* __restrict__ out)
{
  __shared__ __align__(16) bf16 As[2][128][64];
  __shared__ __align__(16) bf16 Bs[2][128][64];
  const int tid  = threadIdx.x;
  const int lane = tid & 63, wid = tid >> 6;
  const int l15  = lane & 15, lg = lane >> 4;
  const int L  = (blockIdx.x & 7) * 64 + (blockIdx.x >> 3);
  const int m0 = (L >> 3) * 128, n0 = (L & 7) * 128;
  const int wm = wid >> 1, wn = wid & 1;
  const char* Ab = (const char*)A;
  const char* Wb = (const char*)W;

  f32x4 acc[4][4] = {};

  GSTAGE(0, 0);
  asm volatile("s_waitcnt vmcnt(0)" ::: "memory");
  __syncthreads();

  int cur = 0;
  for (int t = 0; t < 16; ++t) {
    if (t + 1 < 16) GSTAGE((t + 1) << 6, cur ^ 1);

    bf16x8 af[4][2], bfr[4][2];
    #pragma unroll
    for (int i = 0; i < 4; ++i) {
      const int ra = wm * 64 + i * 16 + l15;
      const int rb = wn * 64 + i * 16 + l15;
      #pragma unroll
      for (int s = 0; s < 2; ++s) {
        const int co = (s * 64 + lg * 16);
        af[i][s]  = *reinterpret_cast<const bf16x8*>(
            (const char*)&As[cur][0][0] + ra * 128 + (co ^ ((ra & 7) << 4)));
        bfr[i][s] = *reinterpret_cast<const bf16x8*>(
            (const char*)&Bs[cur][0][0] + rb * 128 + (co ^ ((rb & 7) << 4)));
      }
    }
    __builtin_amdgcn_s_setprio(1);
    #pragma unroll
    for (int s = 0; s < 2; ++s)
      #pragma unroll
      for (int mi = 0; mi < 4; ++mi)
        #pragma unroll
        for (int ni = 0; ni < 4; ++ni)
          acc[mi][ni] = __builtin_amdgcn_mfma_f32_16x16x32_bf16(af[mi][s], bfr[ni][s], acc[mi][ni], 0, 0, 0);
    __builtin_amdgcn_s_setprio(0);

    asm volatile("s_waitcnt vmcnt(0)" ::: "memory");
    __syncthreads();
    cur ^= 1;
  }

  #pragma unroll
  for (int ni = 0; ni < 4; ++ni) {
    const int col = n0 + wn * 64 + ni * 16 + l15;
    const float bi = bias[col];
    #pragma unroll
    for (int mi = 0; mi < 4; ++mi) {
      const int row0 = m0 + wm * 64 + mi * 16 + lg * 4;
      #pragma unroll
      for (int r = 0; r < 4; ++r)
        out[(size_t)(row0 + r) * DIM + col] = acc[mi][ni][r] + bi;
    }
  }
}

// ---------------------------------------------------------------------------
// Flash attention: round-12 structure + mask via 16-entry u64 LDS LUT
// (nibble -> prepacked (m01,m23) AND-masks). Replaces the ~14-op sext chain
// per (qg,nf) with shift+and+ds_read_b64 (~6 ops) -- ~110 VALU ops/tile saved.
// ---------------------------------------------------------------------------
__global__ __launch_bounds__(512, 4)
void attn_fwd(const bf16* __restrict__ Qb, const bf16* __restrict__ Kb,
              const bf16* __restrict__ Vt, const u64* __restrict__ mbits,
              bf16* __restrict__ ctx)
{
  __shared__ __align__(16) bf16 Kbuf[2][64][64];
  __shared__ __align__(16) bf16 Vbuf[2][64][64];
  __shared__ u64 lutm[16];

  const int tid  = threadIdx.x;
  const int lane = tid & 63;
  const int l15  = lane & 15, lg = lane >> 4;
  const int L  = (blockIdx.x & 7) * 64 + (blockIdx.x >> 3);
  const int qi = L & 7;
  const int hb = L >> 3;
  const int h  = hb & 15, b = hb >> 4;
  const int w  = tid >> 6;
  const int qbase = qi * 256 + w * 32;

  if (tid < 16) {
    lutm[tid] = ((tid & 1) ? 0xFFFFull : 0) | ((tid & 2) ? 0xFFFF0000ull : 0)
              | ((tid & 4) ? 0xFFFF00000000ull : 0)
              | ((tid & 8) ? 0xFFFF000000000000ull : 0);
  }

  const int rr_s = tid >> 3;
  const int cG_s = ((tid & 7) << 4) ^ ((rr_s & 7) << 4);
  const char* gk = (const char*)Kb + ((size_t)(b * S_LEN + rr_s) * DIM + h * DK) * 2 + cG_s;
  const char* gv = (const char*)Vt + ((size_t)b * DIM + h * DK + rr_s) * (S_LEN * 2) + cG_s;
  char* lK = (char*)&Kbuf[0][0][0] + tid * 16;
  char* lV = (char*)&Vbuf[0][0][0] + tid * 16;

  const unsigned xo  = (l15 & 7) << 4;
  const unsigned ko0 = l15 * 128 + ((lg * 16) ^ xo);
  const unsigned ko1 = l15 * 128 + (((64 + lg * 16)) ^ xo);
  const char* KB = (const char*)&Kbuf[0][0][0];
  const char* VB = (const char*)&Vbuf[0][0][0];

  bf16x8 qf[2][2];
  #pragma unroll
  for (int qg = 0; qg < 2; ++qg) {
    const size_t qrow = (size_t)b * S_LEN + qbase + qg * 16 + l15;
    #pragma unroll
    for (int s = 0; s < 2; ++s)
      qf[qg][s] = *reinterpret_cast<const bf16x8*>(&Qb[qrow * DIM + h * DK + s * 32 + lg * 8]);
  }

  bf16x8 onesf;
  #pragma unroll
  for (int j = 0; j < 8; ++j) onesf[j] = (bf16)1.0f;

  union pqu { unsigned u[8]; bf16x8 frag[2]; };

  f32x4 o[2][4] = {};
  f32x4 o_l[2] = {};
  const u64* mp0 = mbits + ((size_t)b * S_LEN + qbase + l15) * (S_LEN / 64);
  const u64* mp1 = mp0 + (size_t)16 * (S_LEN / 64);

  gload16(gk, lK);  gload16(gv, lV);
  gk += 64 * DIM * 2;  gv += 64 * 2;
  u64 mbc[2] = { mp0[0], mp1[0] };
  mp0++; mp1++;

  const int NT = S_LEN / 64;   // 32
  for (int t = 0; t < NT; ++t) {
    asm volatile("s_waitcnt vmcnt(0)" ::: "memory");
    __syncthreads();

    u64 mbn[2] = {0, 0};
    if (t + 1 < NT) {
      mbn[0] = *mp0++;
      mbn[1] = *mp1++;
      const unsigned nb = ((t + 1) & 1) << 13;
      gload16(gk, lK + nb);
      gload16(gv, lV + nb);
      gk += 64 * DIM * 2;
      gv += 64 * 2;
    }

    const unsigned tb = (t & 1) << 13;

    f32x4 sc[2][4] = {};
    __builtin_amdgcn_s_setprio(1);
    #pragma unroll
    for (int s = 0; s < 2; ++s) {
      const char* kp = KB + tb + (s ? ko1 : ko0);
      #pragma unroll
      for (int nf = 0; nf < 4; ++nf) {
        bf16x8 kf = *reinterpret_cast<const bf16x8*>(kp + nf * 2048);
        sc[0][nf] = __builtin_amdgcn_mfma_f32_16x16x32_bf16(kf, qf[0][s], sc[0][nf], 0, 0, 0);
        sc[1][nf] = __builtin_amdgcn_mfma_f32_16x16x32_bf16(kf, qf[1][s], sc[1][nf], 0, 0, 0);
      }
    }
    __builtin_amdgcn_s_setprio(0);

    // --- softmax: p = exp2(sc); mask via LDS LUT (nibble -> (m01,m23))
    const u64 sh0 = mbc[0] >> (lg * 4);
    const u64 sh1 = mbc[1] >> (lg * 4);
    pqu W[2];
    #pragma unroll
    for (int qg = 0; qg < 2; ++qg) {
      const u64 sh = qg ? sh1 : sh0;
      #pragma unroll
      for (int nf = 0; nf < 4; ++nf) {
        const unsigned idx = ((unsigned)(sh >> (nf * 16))) & 15u;
        const u64 mk = lutm[idx];
        float e0 = exp2fast(sc[qg][nf][0]);
        float e1 = exp2fast(sc[qg][nf][1]);
        float e2 = exp2fast(sc[qg][nf][2]);
        float e3 = exp2fast(sc[qg][nf][3]);
        W[qg].u[nf * 2 + 0] = cvt_pk_bf16(e0, e1) & (unsigned)mk;
        W[qg].u[nf * 2 + 1] = cvt_pk_bf16(e2, e3) & (unsigned)(mk >> 32);
      }
    }

    __builtin_amdgcn_s_setprio(1);
    #pragma unroll
    for (int s = 0; s < 2; ++s) {
      const char* vp = VB + tb + (s ? ko1 : ko0);
      #pragma unroll
      for (int nf = 0; nf < 4; ++nf) {
        bf16x8 vf = *reinterpret_cast<const bf16x8*>(vp + nf * 2048);
        o[0][nf] = __builtin_amdgcn_mfma_f32_16x16x32_bf16(W[0].frag[s], vf, o[0][nf], 0, 0, 0);
        o[1][nf] = __builtin_amdgcn_mfma_f32_16x16x32_bf16(W[1].frag[s], vf, o[1][nf], 0, 0, 0);
      }
      o_l[0] = __builtin_amdgcn_mfma_f32_16x16x32_bf16(W[0].frag[s], onesf, o_l[0], 0, 0, 0);
      o_l[1] = __builtin_amdgcn_mfma_f32_16x16x32_bf16(W[1].frag[s], onesf, o_l[1], 0, 0, 0);
    }
    __builtin_amdgcn_s_setprio(0);

    mbc[0] = mbn[0]; mbc[1] = mbn[1];
  }

  #pragma unroll
  for (int qg = 0; qg < 2; ++qg) {
    float lf[4];
    #pragma unroll
    for (int r = 0; r < 4; ++r) lf[r] = 1.0f / o_l[qg][r];
    #pragma unroll
    for (int nf = 0; nf < 4; ++nf)
      #pragma unroll
      for (int r = 0; r < 4; ++r) {
        const int q = qbase + qg * 16 + lg * 4 + r;
        ctx[((size_t)b * S_LEN + q) * DIM + h * DK + nf * 16 + l15] = (bf16)(o[qg][nf][r] * lf[r]);
      }
  }
}

// ---------------------------------------------------------------------------
extern "C" void kernel_launch(void* const* d_in, const int* in_sizes, int n_in,
                              void* d_out, int out_size, void* d_ws, size_t ws_size,
                              hipStream_t stream)
{
  const float* q    = (const float*)d_in[0];
  const float* k    = (const float*)d_in[1];
  const float* v    = (const float*)d_in[2];
  const int*   mask = (const int*)  d_in[3];
  const float* Wq   = (const float*)d_in[4];
  const float* bq   = (const float*)d_in[5];
  const float* Wk   = (const float*)d_in[6];
  const float* bk   = (const float*)d_in[7];
  const float* Wv   = (const float*)d_in[8];
  const float* bv   = (const float*)d_in[9];
  const float* Wo   = (const float*)d_in[10];
  const float* bo   = (const float*)d_in[11];
  float* out = (float*)d_out;

  const size_t NE = (size_t)BATCH * S_LEN * DIM;  // 8.39M elements
  const size_t NW = (size_t)DIM * DIM;            // 1.05M elements
  bf16* qB  = (bf16*)d_ws;                        // bf16 copies of inputs
  bf16* kB  = qB + NE;
  bf16* vB  = kB + NE;
  bf16* Qb  = vB + NE;                            // projected Q,K,V
  bf16* Kb  = Qb + NE;
  bf16* Vt  = Kb + NE;
  bf16* WqB = Vt + NE;                            // bf16 weights
  bf16* WkB = WqB + NW;
  bf16* WvB = WkB + NW;
  bf16* WoB = WvB + NW;
  u64*  bits = (u64*)(WoB + NW);                  // 2 MB
  bf16* ctx = qB;                                 // reuse: qB dead after QKV GEMMs

  conv_pack<<<dim3(4096, 5), 256, 0, stream>>>(q, k, v, Wq, Wk, Wv, Wo,
                                               qB, kB, vB, WqB, WkB, WvB, WoB,
                                               mask, bits);

  gemm_qkv<<<1536, 256, 0, stream>>>(qB, kB, vB, WqB, WkB, WvB,
                                     bq, bk, bv, Qb, Kb, Vt);

  attn_fwd<<<512, 512, 0, stream>>>(Qb, Kb, Vt, bits, ctx);

  gemm_out<<<512, 256, 0, stream>>>(ctx, WoB, bo, out);
}

// Round 17
// 217.561 us; speedup vs baseline: 1.2388x; 1.0268x over previous
//
#include <hip/hip_runtime.h>
#include <math.h>

#define S_LEN 2048
#define DIM   1024
#define HEADS 16
#define DK    64
#define BATCH 4

typedef __bf16 bf16;
typedef bf16  bf16x8 __attribute__((ext_vector_type(8)));
typedef bf16  bf16x4 __attribute__((ext_vector_type(4)));
typedef float f32x4  __attribute__((ext_vector_type(4)));
typedef unsigned long long u64;

#define QSCALE (0.125f * 1.44269504088896f)   // 1/sqrt(dk) * log2(e)

__device__ __forceinline__ void gload16(const void* g, void* l) {
  __builtin_amdgcn_global_load_lds((const __attribute__((address_space(1))) void*)g,
                                   (__attribute__((address_space(3))) void*)l, 16, 0, 0);
}
__device__ __forceinline__ float exp2fast(float x) {
  float r; asm("v_exp_f32 %0, %1" : "=v"(r) : "v"(x)); return r;
}
__device__ __forceinline__ unsigned cvt_pk_bf16(float a, float b) {
  unsigned r; asm("v_cvt_pk_bf16_f32 %0, %1, %2" : "=v"(r) : "v"(a), "v"(b)); return r;
}

// ---------------------------------------------------------------------------
// Combined BW-bound pass: f32->bf16 conversion of all 7 tensors + mask
// bitpack, one dispatch (all short streaming blocks). (unchanged)
// ---------------------------------------------------------------------------
__global__ __launch_bounds__(256)
void conv_pack(const float* __restrict__ q, const float* __restrict__ k,
               const float* __restrict__ v,
               const float* __restrict__ Wq, const float* __restrict__ Wk,
               const float* __restrict__ Wv, const float* __restrict__ Wo,
               bf16* __restrict__ qB, bf16* __restrict__ kB, bf16* __restrict__ vB,
               bf16* __restrict__ WqB, bf16* __restrict__ WkB,
               bf16* __restrict__ WvB, bf16* __restrict__ WoB,
               const int* __restrict__ mask, u64* __restrict__ bits)
{
  const int y = blockIdx.y;
  if (y == 4) {
    const int lane = threadIdx.x & 63;
    const size_t w0 = (size_t)blockIdx.x * 64 + (threadIdx.x >> 6);
    #pragma unroll
    for (int it = 0; it < 16; ++it) {
      const size_t w = w0 + it * 4;
      const u64 bb = __ballot(mask[w * 64 + lane] != 0);
      if (lane == 0) bits[w] = bb;
    }
    return;
  }
  const float* in;
  bf16* out;
  size_t idx;
  if (y < 3) {
    in  = (y == 0) ? q  : (y == 1) ? k  : v;
    out = (y == 0) ? qB : (y == 1) ? kB : vB;
    idx = ((size_t)blockIdx.x * 256 + threadIdx.x) * 8;
  } else {
    if (blockIdx.x >= 2048) return;
    const int wsel = blockIdx.x >> 9, inner = blockIdx.x & 511;
    in  = (wsel == 0) ? Wq  : (wsel == 1) ? Wk  : (wsel == 2) ? Wv  : Wo;
    out = (wsel == 0) ? WqB : (wsel == 1) ? WkB : (wsel == 2) ? WvB : WoB;
    idx = ((size_t)inner * 256 + threadIdx.x) * 8;
  }
  float4 a = *reinterpret_cast<const float4*>(&in[idx]);
  float4 b = *reinterpret_cast<const float4*>(&in[idx + 4]);
  bf16x8 r;
  r[0] = (bf16)a.x; r[1] = (bf16)a.y; r[2] = (bf16)a.z; r[3] = (bf16)a.w;
  r[4] = (bf16)b.x; r[5] = (bf16)b.y; r[6] = (bf16)b.z; r[7] = (bf16)b.w;
  *reinterpret_cast<bf16x8*>(&out[idx]) = r;
}

// ---------------------------------------------------------------------------
// Merged QKV GEMMs: BK=32, THREE LDS buffers (48 KB, 3 blocks/CU), stage
// depth 2, counted vmcnt (never 0 in steady loop -- AITER pattern):
//   iter t: stage(t+2) -> vmcnt(8) [tile t's 4 oldest landed; t+1/t+2's 8
//   stay in flight across raw s_barrier] -> read+MFMA tile t -> s_barrier.
// Buffer (t+2)%3 written while t%3 read (disjoint); barrier #2 protects
// (t+3)%3 == t%3 reuse. LDS row = [A|W] 16B-block XOR-permuted (r&7).
// ---------------------------------------------------------------------------
__global__ __launch_bounds__(256, 3)
void gemm_qkv(const bf16* __restrict__ qB, const bf16* __restrict__ kB,
              const bf16* __restrict__ vB,
              const bf16* __restrict__ WqB, const bf16* __restrict__ WkB,
              const bf16* __restrict__ WvB,
              const float* __restrict__ bq, const float* __restrict__ bk,
              const float* __restrict__ bv,
              bf16* __restrict__ Qb, bf16* __restrict__ Kb,
              bf16* __restrict__ Vt)
{
  __shared__ __align__(16) bf16 AB[3][128][64];   // 48 KB
  const int tid = threadIdx.x;
  const int which = blockIdx.x >> 9;            // 0:Q 1:K 2:V (block-uniform)
  const int inner = blockIdx.x & 511;
  const bf16* A     = (which == 0) ? qB  : (which == 1) ? kB  : vB;
  const bf16* W     = (which == 0) ? WqB : (which == 1) ? WkB : WvB;
  const float* bias = (which == 0) ? bq  : (which == 1) ? bk  : bv;

  const int lane = tid & 63, wid = tid >> 6;
  const int l15  = lane & 15, lg = lane >> 4;
  const int L  = (inner & 7) * 64 + (inner >> 3);   // XCD-chunked
  const int m0 = (L >> 3) * 128, n0 = (L & 7) * 128;
  const int wm = wid >> 1, wn = wid & 1;

  const char* src0; const char* src1; const char* src2; const char* src3;
  char* dst0; char* dst1; char* dst2; char* dst3;
  {
    #define MKCH(J, SRC, DST)                                                  \
      { const int c = (J) * 256 + tid;                                         \
        const int r = c >> 3;                                                  \
        const int g = (c & 7) ^ (r & 7);                                       \
        SRC = ((g < 4) ? (const char*)A + (size_t)(m0 + r) * 2048              \
                       : (const char*)W + (size_t)(n0 + r) * 2048) + (g & 3) * 16; \
        DST = (char*)&AB[0][0][0] + c * 16; }
    MKCH(0, src0, dst0) MKCH(1, src1, dst1) MKCH(2, src2, dst2) MKCH(3, src3, dst3)
    #undef MKCH
  }

  // prologue: stage tiles 0 (buf0) and 1 (buf1); do NOT wait
  gload16(src0, dst0); gload16(src1, dst1); gload16(src2, dst2); gload16(src3, dst3);
  src0 += 64; src1 += 64; src2 += 64; src3 += 64;
  gload16(src0, dst0 + 16384); gload16(src1, dst1 + 16384);
  gload16(src2, dst2 + 16384); gload16(src3, dst3 + 16384);
  src0 += 64; src1 += 64; src2 += 64; src3 += 64;

  const unsigned swz  = (l15 & 7) << 4;
  const unsigned aoff = (unsigned)(wm * 64 + l15) * 128 + ((lg * 16) ^ swz);
  const unsigned boff = (unsigned)(wn * 64 + l15) * 128 + ((64 + lg * 16) ^ swz);
  const char* ABB = (const char*)&AB[0][0][0];

  unsigned tb = 0;            // buffer byte-offset of tile t
  unsigned sb = 2u * 16384;   // buffer byte-offset for staging tile t+2

  f32x4 acc[4][4] = {};

  for (int t = 0; t < 32; ++t) {
    if (t < 30) {
      gload16(src0, dst0 + sb); gload16(src1, dst1 + sb);
      gload16(src2, dst2 + sb); gload16(src3, dst3 + sb);
      src0 += 64; src1 += 64; src2 += 64; src3 += 64;
      asm volatile("s_waitcnt vmcnt(8)" ::: "memory");
    } else if (t == 30) {
      asm volatile("s_waitcnt vmcnt(4)" ::: "memory");
    } else {
      asm volatile("s_waitcnt vmcnt(0)" ::: "memory");
    }
    __builtin_amdgcn_s_barrier();
    asm volatile("" ::: "memory");

    bf16x8 af[4], bfr[4];
    #pragma unroll
    for (int i = 0; i < 4; ++i) {
      af[i]  = *reinterpret_cast<const bf16x8*>(ABB + tb + aoff + i * 2048);
      bfr[i] = *reinterpret_cast<const bf16x8*>(ABB + tb + boff + i * 2048);
    }
    __builtin_amdgcn_s_setprio(1);
    #pragma unroll
    for (int mi = 0; mi < 4; ++mi)
      #pragma unroll
      for (int ni = 0; ni < 4; ++ni)
        acc[mi][ni] = __builtin_amdgcn_mfma_f32_16x16x32_bf16(af[mi], bfr[ni], acc[mi][ni], 0, 0, 0);
    __builtin_amdgcn_s_setprio(0);

    asm volatile("" ::: "memory");
    __builtin_amdgcn_s_barrier();
    asm volatile("" ::: "memory");

    tb = (tb == 2u * 16384) ? 0u : tb + 16384;
    sb = (sb == 2u * 16384) ? 0u : sb + 16384;
  }

  #pragma unroll
  for (int ni = 0; ni < 4; ++ni) {
    const int col = n0 + wn * 64 + ni * 16 + l15;
    const float bi = bias[col];
    #pragma unroll
    for (int mi = 0; mi < 4; ++mi) {
      const int row0 = m0 + wm * 64 + mi * 16 + lg * 4;
      if (which == 0) {
        #pragma unroll
        for (int r = 0; r < 4; ++r)
          Qb[(size_t)(row0 + r) * DIM + col] = (bf16)((acc[mi][ni][r] + bi) * QSCALE);
      } else if (which == 1) {
        #pragma unroll
        for (int r = 0; r < 4; ++r)
          Kb[(size_t)(row0 + r) * DIM + col] = (bf16)(acc[mi][ni][r] + bi);
      } else {
        bf16x4 vv;
        #pragma unroll
        for (int r = 0; r < 4; ++r) vv[r] = (bf16)(acc[mi][ni][r] + bi);
        const int seq = row0 & (S_LEN - 1);
        const int t6  = seq & 63;
        const int p0  = (seq & ~63) + ((t6 >> 5) << 5) + (((t6 >> 2) & 3) << 3)
                      + (((t6 >> 4) & 1) << 2);
        *reinterpret_cast<bf16x4*>(
            &Vt[((size_t)(row0 >> 11) * DIM + col) * S_LEN + p0]) = vv;
      }
    }
  }
}

// ---------------------------------------------------------------------------
// O-projection GEMM (f32 out): same BK=32 3-buffer counted-vmcnt structure.
// ---------------------------------------------------------------------------
__global__ __launch_bounds__(256, 3)
void gemm_out(const bf16* __restrict__ A, const bf16* __restrict__ W,
              const float* __restrict__ bias, float* __restrict__ out)
{
  __shared__ __align__(16) bf16 AB[3][128][64];
  const int tid  = threadIdx.x;
  const int lane = tid & 63, wid = tid >> 6;
  const int l15  = lane & 15, lg = lane >> 4;
  const int L  = (blockIdx.x & 7) * 64 + (blockIdx.x >> 3);
  const int m0 = (L >> 3) * 128, n0 = (L & 7) * 128;
  const int wm = wid >> 1, wn = wid & 1;

  const char* src0; const char* src1; const char* src2; const char* src3;
  char* dst0; char* dst1; char* dst2; char* dst3;
  {
    #define MKCH(J, SRC, DST)                                                  \
      { const int c = (J) * 256 + tid;                                         \
        const int r = c >> 3;                                                  \
        const int g = (c & 7) ^ (r & 7);                                       \
        SRC = ((g < 4) ? (const char*)A + (size_t)(m0 + r) * 2048              \
                       : (const char*)W + (size_t)(n0 + r) * 2048) + (g & 3) * 16; \
        DST = (char*)&AB[0][0][0] + c * 16; }
    MKCH(0, src0, dst0) MKCH(1, src1, dst1) MKCH(2, src2, dst2) MKCH(3, src3, dst3)
    #undef MKCH
  }

  gload16(src0, dst0); gload16(src1, dst1); gload16(src2, dst2); gload16(src3, dst3);
  src0 += 64; src1 += 64; src2 += 64; src3 += 64;
  gload16(src0, dst0 + 16384); gload16(src1, dst1 + 16384);
  gload16(src2, dst2 + 16384); gload16(src3, dst3 + 16384);
  src0 += 64; src1 += 64; src2 += 64; src3 += 64;

  const unsigned swz  = (l15 & 7) << 4;
  const unsigned aoff = (unsigned)(wm * 64 + l15) * 128 + ((lg * 16) ^ swz);
  const unsigned boff = (unsigned)(wn * 64 + l15) * 128 + ((64 + lg * 16) ^ swz);
  const char* ABB = (const char*)&AB[0][0][0];

  unsigned tb = 0;
  unsigned sb = 2u * 16384;

  f32x4 acc[4][4] = {};

  for (int t = 0; t < 32; ++t) {
    if (t < 30) {
      gload16(src0, dst0 + sb); gload16(src1, dst1 + sb);
      gload16(src2, dst2 + sb); gload16(src3, dst3 + sb);
      src0 += 64; src1 += 64; src2 += 64; src3 += 64;
      asm volatile("s_waitcnt vmcnt(8)" ::: "memory");
    } else if (t == 30) {
      asm volatile("s_waitcnt vmcnt(4)" ::: "memory");
    } else {
      asm volatile("s_waitcnt vmcnt(0)" ::: "memory");
    }
    __builtin_amdgcn_s_barrier();
    asm volatile("" ::: "memory");

    bf16x8 af[4], bfr[4];
    #pragma unroll
    for (int i = 0; i < 4; ++i) {
      af[i]  = *reinterpret_cast<const bf16x8*>(ABB + tb + aoff + i * 2048);
      bfr[i] = *reinterpret_cast<const bf16x8*>(ABB + tb + boff + i * 2048);
    }
    __builtin_amdgcn_s_setprio(1);
    #pragma unroll
    for (int mi = 0; mi < 4; ++mi)
      #pragma unroll
      for (int ni = 0; ni < 4; ++ni)
        acc[mi][ni] = __builtin_amdgcn_mfma_f32_16x16x32_bf16(af[mi], bfr[ni], acc[mi][ni], 0, 0, 0);
    __builtin_amdgcn_s_setprio(0);

    asm volatile("" ::: "memory");
    __builtin_amdgcn_s_barrier();
    asm volatile("" ::: "memory");

    tb = (tb == 2u * 16384) ? 0u : tb + 16384;
    sb = (sb == 2u * 16384) ? 0u : sb + 16384;
  }

  #pragma unroll
  for (int ni = 0; ni < 4; ++ni) {
    const int col = n0 + wn * 64 + ni * 16 + l15;
    const float bi = bias[col];
    #pragma unroll
    for (int mi = 0; mi < 4; ++mi) {
      const int row0 = m0 + wm * 64 + mi * 16 + lg * 4;
      #pragma unroll
      for (int r = 0; r < 4; ++r)
        out[(size_t)(row0 + r) * DIM + col] = acc[mi][ni][r] + bi;
    }
  }
}

// ---------------------------------------------------------------------------
// Flash attention (round-16, unchanged): static-max softmax, prescaled Q,
// P in registers via cvt_pk + k-permuted V, hoisted addresses, mask via
// 16-entry u64 LDS LUT, double-buffered K/V via global_load_lds + XOR swz.
// ---------------------------------------------------------------------------
__global__ __launch_bounds__(512, 4)
void attn_fwd(const bf16* __restrict__ Qb, const bf16* __restrict__ Kb,
              const bf16* __restrict__ Vt, const u64* __restrict__ mbits,
              bf16* __restrict__ ctx)
{
  __shared__ __align__(16) bf16 Kbuf[2][64][64];
  __shared__ __align__(16) bf16 Vbuf[2][64][64];
  __shared__ u64 lutm[16];

  const int tid  = threadIdx.x;
  const int lane = tid & 63;
  const int l15  = lane & 15, lg = lane >> 4;
  const int L  = (blockIdx.x & 7) * 64 + (blockIdx.x >> 3);
  const int qi = L & 7;
  const int hb = L >> 3;
  const int h  = hb & 15, b = hb >> 4;
  const int w  = tid >> 6;
  const int qbase = qi * 256 + w * 32;

  if (tid < 16) {
    lutm[tid] = ((tid & 1) ? 0xFFFFull : 0) | ((tid & 2) ? 0xFFFF0000ull : 0)
              | ((tid & 4) ? 0xFFFF00000000ull : 0)
              | ((tid & 8) ? 0xFFFF000000000000ull : 0);
  }

  const int rr_s = tid >> 3;
  const int cG_s = ((tid & 7) << 4) ^ ((rr_s & 7) << 4);
  const char* gk = (const char*)Kb + ((size_t)(b * S_LEN + rr_s) * DIM + h * DK) * 2 + cG_s;
  const char* gv = (const char*)Vt + ((size_t)b * DIM + h * DK + rr_s) * (S_LEN * 2) + cG_s;
  char* lK = (char*)&Kbuf[0][0][0] + tid * 16;
  char* lV = (char*)&Vbuf[0][0][0] + tid * 16;

  const unsigned xo  = (l15 & 7) << 4;
  const unsigned ko0 = l15 * 128 + ((lg * 16) ^ xo);
  const unsigned ko1 = l15 * 128 + (((64 + lg * 16)) ^ xo);
  const char* KB = (const char*)&Kbuf[0][0][0];
  const char* VB = (const char*)&Vbuf[0][0][0];

  bf16x8 qf[2][2];
  #pragma unroll
  for (int qg = 0; qg < 2; ++qg) {
    const size_t qrow = (size_t)b * S_LEN + qbase + qg * 16 + l15;
    #pragma unroll
    for (int s = 0; s < 2; ++s)
      qf[qg][s] = *reinterpret_cast<const bf16x8*>(&Qb[qrow * DIM + h * DK + s * 32 + lg * 8]);
  }

  bf16x8 onesf;
  #pragma unroll
  for (int j = 0; j < 8; ++j) onesf[j] = (bf16)1.0f;

  union pqu { unsigned u[8]; bf16x8 frag[2]; };

  f32x4 o[2][4] = {};
  f32x4 o_l[2] = {};
  const u64* mp0 = mbits + ((size_t)b * S_LEN + qbase + l15) * (S_LEN / 64);
  const u64* mp1 = mp0 + (size_t)16 * (S_LEN / 64);

  gload16(gk, lK);  gload16(gv, lV);
  gk += 64 * DIM * 2;  gv += 64 * 2;
  u64 mbc[2] = { mp0[0], mp1[0] };
  mp0++; mp1++;

  const int NT = S_LEN / 64;   // 32
  for (int t = 0; t < NT; ++t) {
    asm volatile("s_waitcnt vmcnt(0)" ::: "memory");
    __syncthreads();

    u64 mbn[2] = {0, 0};
    if (t + 1 < NT) {
      mbn[0] = *mp0++;
      mbn[1] = *mp1++;
      const unsigned nb = ((t + 1) & 1) << 13;
      gload16(gk, lK + nb);
      gload16(gv, lV + nb);
      gk += 64 * DIM * 2;
      gv += 64 * 2;
    }

    const unsigned tb = (t & 1) << 13;

    f32x4 sc[2][4] = {};
    __builtin_amdgcn_s_setprio(1);
    #pragma unroll
    for (int s = 0; s < 2; ++s) {
      const char* kp = KB + tb + (s ? ko1 : ko0);
      #pragma unroll
      for (int nf = 0; nf < 4; ++nf) {
        bf16x8 kf = *reinterpret_cast<const bf16x8*>(kp + nf * 2048);
        sc[0][nf] = __builtin_amdgcn_mfma_f32_16x16x32_bf16(kf, qf[0][s], sc[0][nf], 0, 0, 0);
        sc[1][nf] = __builtin_amdgcn_mfma_f32_16x16x32_bf16(kf, qf[1][s], sc[1][nf], 0, 0, 0);
      }
    }
    __builtin_amdgcn_s_setprio(0);

    const u64 sh0 = mbc[0] >> (lg * 4);
    const u64 sh1 = mbc[1] >> (lg * 4);
    pqu W[2];
    #pragma unroll
    for (int qg = 0; qg < 2; ++qg) {
      const u64 sh = qg ? sh1 : sh0;
      #pragma unroll
      for (int nf = 0; nf < 4; ++nf) {
        const unsigned idx = ((unsigned)(sh >> (nf * 16))) & 15u;
        const u64 mk = lutm[idx];
        float e0 = exp2fast(sc[qg][nf][0]);
        float e1 = exp2fast(sc[qg][nf][1]);
        float e2 = exp2fast(sc[qg][nf][2]);
        float e3 = exp2fast(sc[qg][nf][3]);
        W[qg].u[nf * 2 + 0] = cvt_pk_bf16(e0, e1) & (unsigned)mk;
        W[qg].u[nf * 2 + 1] = cvt_pk_bf16(e2, e3) & (unsigned)(mk >> 32);
      }
    }

    __builtin_amdgcn_s_setprio(1);
    #pragma unroll
    for (int s = 0; s < 2; ++s) {
      const char* vp = VB + tb + (s ? ko1 : ko0);
      #pragma unroll
      for (int nf = 0; nf < 4; ++nf) {
        bf16x8 vf = *reinterpret_cast<const bf16x8*>(vp + nf * 2048);
        o[0][nf] = __builtin_amdgcn_mfma_f32_16x16x32_bf16(W[0].frag[s], vf, o[0][nf], 0, 0, 0);
        o[1][nf] = __builtin_amdgcn_mfma_f32_16x16x32_bf16(W[1].frag[s], vf, o[1][nf], 0, 0, 0);
      }
      o_l[0] = __builtin_amdgcn_mfma_f32_16x16x32_bf16(W[0].frag[s], onesf, o_l[0], 0, 0, 0);
      o_l[1] = __builtin_amdgcn_mfma_f32_16x16x32_bf16(W[1].frag[s], onesf, o_l[1], 0, 0, 0);
    }
    __builtin_amdgcn_s_setprio(0);

    mbc[0] = mbn[0]; mbc[1] = mbn[1];
  }

  #pragma unroll
  for (int qg = 0; qg < 2; ++qg) {
    float lf[4];
    #pragma unroll
    for (int r = 0; r < 4; ++r) lf[r] = 1.0f / o_l[qg][r];
    #pragma unroll
    for (int nf = 0; nf < 4; ++nf)
      #pragma unroll
      for (int r = 0; r < 4; ++r) {
        const int q = qbase + qg * 16 + lg * 4 + r;
        ctx[((size_t)b * S_LEN + q) * DIM + h * DK + nf * 16 + l15] = (bf16)(o[qg][nf][r] * lf[r]);
      }
  }
}

// ---------------------------------------------------------------------------
extern "C" void kernel_launch(void* const* d_in, const int* in_sizes, int n_in,
                              void* d_out, int out_size, void* d_ws, size_t ws_size,
                              hipStream_t stream)
{
  const float* q    = (const float*)d_in[0];
  const float* k    = (const float*)d_in[1];
  const float* v    = (const float*)d_in[2];
  const int*   mask = (const int*)  d_in[3];
  const float* Wq   = (const float*)d_in[4];
  const float* bq   = (const float*)d_in[5];
  const float* Wk   = (const float*)d_in[6];
  const float* bk   = (const float*)d_in[7];
  const float* Wv   = (const float*)d_in[8];
  const float* bv   = (const float*)d_in[9];
  const float* Wo   = (const float*)d_in[10];
  const float* bo   = (const float*)d_in[11];
  float* out = (float*)d_out;

  const size_t NE = (size_t)BATCH * S_LEN * DIM;  // 8.39M elements
  const size_t NW = (size_t)DIM * DIM;            // 1.05M elements
  bf16* qB  = (bf16*)d_ws;                        // bf16 copies of inputs
  bf16* kB  = qB + NE;
  bf16* vB  = kB + NE;
  bf16* Qb  = vB + NE;                            // projected Q,K,V
  bf16* Kb  = Qb + NE;
  bf16* Vt  = Kb + NE;
  bf16* WqB = Vt + NE;                            // bf16 weights
  bf16* WkB = WqB + NW;
  bf16* WvB = WkB + NW;
  bf16* WoB = WvB + NW;
  u64*  bits = (u64*)(WoB + NW);                  // 2 MB
  bf16* ctx = qB;                                 // reuse: qB dead after QKV GEMMs

  conv_pack<<<dim3(4096, 5), 256, 0, stream>>>(q, k, v, Wq, Wk, Wv, Wo,
                                               qB, kB, vB, WqB, WkB, WvB, WoB,
                                               mask, bits);

  gemm_qkv<<<1536, 256, 0, stream>>>(qB, kB, vB, WqB, WkB, WvB,
                                     bq, bk, bv, Qb, Kb, Vt);

  attn_fwd<<<512, 512, 0, stream>>>(Qb, Kb, Vt, bits, ctx);

  gemm_out<<<512, 256, 0, stream>>>(ctx, WoB, bo, out);
}